// Round 1
// 2140.647 us; speedup vs baseline: 1.4051x; 1.4051x over previous
//
#include <hip/hip_runtime.h>
#include <stdint.h>

typedef unsigned short ushort_t;

#define NN    2048
#define DIMC  256
#define H1    1030
#define MD    64
#define NROWS 8192

// edge MFMA tiling
#define KPAD     1088        // 2*544, multiple of 32, >= H1
#define CH       544         // K-chunk held in LDS
#define CH_STEPS 17          // 544/32
#define APAD     552         // LDS row stride (bf16 elems): 552*2B=1104B=276 dwords, 276%32=20 -> conflict-free b128

typedef __bf16 bf16x8 __attribute__((ext_vector_type(8)));
typedef float  f32x4  __attribute__((ext_vector_type(4)));

__device__ __forceinline__ float bfu2f(ushort_t u){ union{unsigned u; float f;} v; v.u = ((unsigned)u)<<16; return v.f; }
__device__ __forceinline__ ushort_t f2bfu(float f){ union{float f; unsigned u;} v; v.f=f; unsigned r = (v.u + 0x7FFFu + ((v.u>>16)&1u))>>16; return (ushort_t)r; }
__device__ __forceinline__ float siluf(float x){ return x / (1.0f + __expf(-x)); }

__global__ void mask_kernel(const int* __restrict__ mask, float* __restrict__ out_mask){
    int t = blockIdx.x*256 + threadIdx.x;
    if (t < NROWS) out_mask[t] = mask[t] ? 1.0f : 0.0f;
}

// ---------------- adj scan: bool->f32 passthrough + neighbor extraction + pair emission ----------------
// Selection semantics (VALID_RADIUS=0): self (ranking -1) + adjacency-non-self (ranking 0),
// truncated to the 15 lowest-index adjacency neighbors (top_k K=16, stable ties).
// Contribution requires mask[i] (self) and mask[i]&mask[j] (neighbor).
__global__ void adj_kernel(const int* __restrict__ adj, const int* __restrict__ mask,
                           float* __restrict__ out_adj, int* __restrict__ pairs,
                           int* __restrict__ counter)
{
    const int w = threadIdx.x >> 6, lane = threadIdx.x & 63;
    const int row = blockIdx.x*4 + w;
    const int b = row >> 11, i = row & (NN-1);
    __shared__ int nbrs[4][15];
    int total = 0;
    const size_t rbase = (size_t)row * NN;
    for (int c = 0; c < NN/64; c++) {
        int j = c*64 + lane;
        int v = adj[rbase + j];
        out_adj[rbase + j] = v ? 1.0f : 0.0f;
        bool pred = (v != 0) && (j != i);
        unsigned long long bm = __ballot(pred);
        if (pred) {
            int slot = total + __popcll(bm & ((1ull<<lane)-1ull));
            if (slot < 15) nbrs[w][slot] = j;
        }
        total += __popcll(bm);
    }
    int cnt = total < 15 ? total : 15;
    if (mask[row] != 0) {
        int jl = (lane < cnt) ? nbrs[w][lane] : 0;
        bool ok = (lane < cnt) && (mask[b*NN + jl] != 0);
        unsigned long long bm = __ballot(ok);
        int npair = 1 + __popcll(bm);
        int basep = 0;
        if (lane == 0) basep = atomicAdd(counter, npair);
        basep = __shfl(basep, 0);
        if (lane == 0) pairs[basep] = (row << 16) | i;      // self pair
        if (ok) {
            int pos = basep + 1 + __popcll(bm & ((1ull<<lane)-1ull));
            pairs[pos] = (row << 16) | jl;
        }
    }
}

// ---------------- P/Q precompute (scalar fp32): P = emb @ eW1[0:256], Q = emb @ eW1[256:512] ----
__global__ void gemm_pq(const float* __restrict__ emb, const float* __restrict__ eW1,
                        ushort_t* __restrict__ Pb, ushort_t* __restrict__ Qb)
{
    size_t t = (size_t)blockIdx.x*256 + threadIdx.x;
    const size_t PER = (size_t)NROWS * H1;
    if (t >= 2*PER) return;
    int which = (int)(t / PER);
    size_t rem = t - (size_t)which*PER;
    int r = (int)(rem / H1), c = (int)(rem % H1);
    const float* a = emb + (size_t)r*DIMC;
    const float* bcol = eW1 + (size_t)(which*256)*H1 + c;
    float acc = 0.f;
#pragma unroll 4
    for (int k = 0; k < DIMC; k++) acc += a[k] * bcol[(size_t)k*H1];
    (which ? Qb : Pb)[rem] = f2bfu(acc);
}

// ---------------- eW2 transpose to bf16 [MD][KPAD], zero-padded for k >= H1 ----------------
__global__ void w2t_kernel(const float* __restrict__ eW2, ushort_t* __restrict__ W2T)
{
    int t = blockIdx.x*256 + threadIdx.x;
    if (t >= MD*KPAD) return;
    int n = t / KPAD, k = t - n*KPAD;
    float v = (k < H1) ? eW2[(size_t)k*MD + n] : 0.0f;
    W2T[t] = f2bfu(v);
}

// ---------------- edge MLP, 16 pairs per block, MFMA for h @ eW2 ----------------
// Phase A: h[p][c] = silu(P[row_p][c] + Q[jr_p][c] + d*w512[c] + f0*w513[c] + f1*w514[c] + eb1[c])
//          stored in LDS as bf16 hi + bf16 lo (hi+lo ~= f32 h, so no precision loss on A side).
// Phase B: 16x64 = [16 x K] @ W2T^T via mfma_f32_16x16x32_bf16, 2 passes (hi, lo), acc f32.
__global__ __launch_bounds__(256)
void edge_mfma(const int* __restrict__ pairs, const int* __restrict__ counter,
               const ushort_t* __restrict__ P, const ushort_t* __restrict__ Q,
               const float* __restrict__ coors, const float* __restrict__ feat,
               const float* __restrict__ eW1, const float* __restrict__ eb1,
               const ushort_t* __restrict__ W2T, const float* __restrict__ eb2,
               float* __restrict__ macc)
{
    const int np = counter[0];
    const int base = blockIdx.x * 16;
    if (base >= np) return;

    __shared__ ushort_t Ahi[16][APAD];
    __shared__ ushort_t Alo[16][APAD];
    __shared__ int   s_row[16];
    __shared__ int   s_jr[16];
    __shared__ int   s_val[16];
    __shared__ float s_d[16], s_f0[16], s_f1[16];

    const int t = threadIdx.x;
    const int lane = t & 63;
    const int w = t >> 6;            // wave id 0..3

    if (t < 16) {
        int ip = base + t;
        int valid = (ip < np) ? 1 : 0;
        int e = valid ? pairs[ip] : 0;
        int row = e >> 16, j = e & 0xFFFF;
        int jr = ((row >> 11) << 11) + j;
        float dx = coors[(size_t)row*3+0] - coors[(size_t)jr*3+0];
        float dy = coors[(size_t)row*3+1] - coors[(size_t)jr*3+1];
        float dz = coors[(size_t)row*3+2] - coors[(size_t)jr*3+2];
        size_t fo = ((size_t)row*NN + j)*2;
        s_row[t] = row; s_jr[t] = jr; s_val[t] = valid;
        s_d[t] = dx*dx + dy*dy + dz*dz;
        s_f0[t] = feat[fo]; s_f1[t] = feat[fo+1];
    }
    __syncthreads();

    // wave w owns pairs 4w..4w+3 in phase A; pull their metadata into registers
    int prow[4], pjr[4];
    float pd[4], pf0[4], pf1[4];
#pragma unroll
    for (int p4 = 0; p4 < 4; p4++) {
        int p = w*4 + p4;
        prow[p4] = s_row[p]; pjr[p4] = s_jr[p];
        pd[p4] = s_d[p]; pf0[p4] = s_f0[p]; pf1[p4] = s_f1[p];
    }

    const float* w512 = eW1 + (size_t)512*H1;
    const float* w513 = eW1 + (size_t)513*H1;
    const float* w514 = eW1 + (size_t)514*H1;

    f32x4 acc = {0.f, 0.f, 0.f, 0.f};

    const int m16  = lane & 15;      // phase B: A-row (pair) / B-col within tile
    const int kg   = lane >> 4;      // phase B: k-group 0..3
    const int ncol = w*16 + m16;     // output column owned by this lane's wave tile
    const ushort_t* wrowbase = W2T + (size_t)ncol * KPAD + kg*8;

    for (int chunk = 0; chunk < 2; chunk++) {
        const int c0 = chunk * CH;
        // ---- phase A: fill Ahi/Alo rows 4w..4w+3, cols [0,CH) ----
        for (int i = 0; i < 9; i++) {
            int c = i*64 + lane;
            if (c < CH) {
                int cc = c0 + c;
                bool inK = cc < H1;
                float a512 = 0.f, a513 = 0.f, a514 = 0.f, ab = 0.f;
                if (inK) { a512 = w512[cc]; a513 = w513[cc]; a514 = w514[cc]; ab = eb1[cc]; }
#pragma unroll
                for (int p4 = 0; p4 < 4; p4++) {
                    float h = 0.f;
                    if (inK) {
                        float pv = bfu2f(P[(size_t)prow[p4]*H1 + cc]);
                        float qv = bfu2f(Q[(size_t)pjr[p4]*H1 + cc]);
                        float x = pv + qv + pd[p4]*a512 + pf0[p4]*a513 + pf1[p4]*a514 + ab;
                        h = siluf(x);
                    }
                    ushort_t hi = f2bfu(h);
                    float hif = bfu2f(hi);
                    ushort_t lo = f2bfu(h - hif);
                    int p = w*4 + p4;
                    Ahi[p][c] = hi;
                    Alo[p][c] = lo;
                }
            }
        }
        __syncthreads();
        // ---- phase B: acc += A_chunk @ W2T_chunk^T (hi and lo passes) ----
        const ushort_t* wrow = wrowbase + c0;
#pragma unroll 4
        for (int ks = 0; ks < CH_STEPS; ks++) {
            int k = ks*32 + kg*8;
            bf16x8 ahi = *reinterpret_cast<const bf16x8*>(&Ahi[m16][k]);
            bf16x8 alo = *reinterpret_cast<const bf16x8*>(&Alo[m16][k]);
            bf16x8 bfr = *reinterpret_cast<const bf16x8*>(wrow + ks*32);
            acc = __builtin_amdgcn_mfma_f32_16x16x32_bf16(ahi, bfr, acc, 0, 0, 0);
            acc = __builtin_amdgcn_mfma_f32_16x16x32_bf16(alo, bfr, acc, 0, 0, 0);
        }
        __syncthreads();
    }

    // ---- epilogue: D[m][n], m = kg*4 + r (pair), n = ncol ----
    {
        float bias = eb2[ncol];
#pragma unroll
        for (int r = 0; r < 4; r++) {
            int p = kg*4 + r;
            if (s_val[p]) {
                float m = siluf(acc[r] + bias);
                atomicAdd(&macc[(size_t)s_row[p]*MD + ncol], m);
            }
        }
    }
}

// ---------------- node MLP layer 1 (scalar fp32): hidden = silu([emb||m_i] @ nW1 + nb1) ----
__global__ void node1_kernel(const float* __restrict__ emb, const float* __restrict__ macc,
                             const float* __restrict__ nW1, const float* __restrict__ nb1,
                             float* __restrict__ hidden)
{
    size_t t = (size_t)blockIdx.x*256 + threadIdx.x;
    if (t >= (size_t)NROWS*512) return;
    int r = (int)(t / 512), c = (int)(t % 512);
    const float* a = emb + (size_t)r*DIMC;
    const float* m = macc + (size_t)r*MD;
    float acc = nb1[c];
#pragma unroll 4
    for (int k = 0; k < DIMC; k++) acc += a[k] * nW1[(size_t)k*512 + c];
#pragma unroll 4
    for (int k = 0; k < MD; k++)   acc += m[k] * nW1[(size_t)(DIMC+k)*512 + c];
    hidden[t] = siluf(acc);
}

// ---------------- node MLP layer 2 (scalar fp32): out = hidden @ nW2 + nb2 + emb (f32 out) ----
__global__ void node2_kernel(const float* __restrict__ hidden, const float* __restrict__ nW2,
                             const float* __restrict__ nb2, const float* __restrict__ emb,
                             float* __restrict__ out_node)
{
    size_t t = (size_t)blockIdx.x*256 + threadIdx.x;
    if (t >= (size_t)NROWS*DIMC) return;
    int r = (int)(t / DIMC), c = (int)(t % DIMC);
    const float* a = hidden + (size_t)r*512;
    float acc = nb2[c];
#pragma unroll 4
    for (int k = 0; k < 512; k++) acc += a[k] * nW2[(size_t)k*DIMC + c];
    out_node[t] = acc + emb[t];
}

extern "C" void kernel_launch(void* const* d_in, const int* in_sizes, int n_in,
                              void* d_out, int out_size, void* d_ws, size_t ws_size,
                              hipStream_t stream)
{
    const float* emb   = (const float*)d_in[0];
    const float* coors = (const float*)d_in[1];
    const int*   adj   = (const int*)d_in[2];
    const float* feat  = (const float*)d_in[3];
    const int*   mask  = (const int*)d_in[4];
    const float* eW1   = (const float*)d_in[5];
    const float* eb1   = (const float*)d_in[6];
    const float* eW2   = (const float*)d_in[7];
    const float* eb2   = (const float*)d_in[8];
    const float* nW1   = (const float*)d_in[9];
    const float* nb1   = (const float*)d_in[10];
    const float* nW2   = (const float*)d_in[11];
    const float* nb2   = (const float*)d_in[12];

    float* out       = (float*)d_out;
    float* out_node  = out;               // [4,2048,256]   2,097,152
    float* out_coors = out + 2097152;     // [4,2048,3]        24,576
    float* out_adj   = out + 2121728;     // [4,2048,2048] 16,777,216
    float* out_feat  = out + 18898944;    // [4,2048,2048,2] 33,554,432
    float* out_mask  = out + 52453376;    // [4,2048]           8,192

    char* ws = (char*)d_ws;
    int*      counter = (int*)(ws + 0);            // 256 B
    float*    macc    = (float*)(ws + 256);        // 8192x64 f32 -> ends 2,097,408
    int*      pairs   = (int*)(ws + 2097408);      // 131072 ints -> ends 2,621,696
    ushort_t* Pbuf    = (ushort_t*)(ws + 2621696); // 8192x1030 bf16 -> ends 19,497,216
    ushort_t* Qbuf    = (ushort_t*)(ws + 19497216);// 8192x1030 bf16 -> ends 36,372,736
    float*    hidden  = (float*)(ws + 2621696);    // 8192x512 f32, REUSES Pbuf region (dead by then)

    // W2T (bf16 [64][1088] = 139,264 B) parked in the out_node region: it is consumed by
    // edge_mfma and fully overwritten afterwards by node2_kernel. Zero workspace growth.
    ushort_t* W2T = (ushort_t*)out_node;

    hipMemsetAsync(counter, 0, 256, stream);
    hipMemsetAsync(macc, 0, (size_t)NROWS*MD*sizeof(float), stream);

    hipMemcpyAsync(out_coors, coors, (size_t)24576*sizeof(float), hipMemcpyDeviceToDevice, stream);
    hipMemcpyAsync(out_feat,  feat,  (size_t)33554432*sizeof(float), hipMemcpyDeviceToDevice, stream);

    mask_kernel<<<(NROWS + 255)/256, 256, 0, stream>>>(mask, out_mask);
    adj_kernel<<<NROWS/4, 256, 0, stream>>>(adj, mask, out_adj, pairs, counter);

    {
        size_t tot = 2ull * NROWS * H1;
        gemm_pq<<<(unsigned)((tot + 255)/256), 256, 0, stream>>>(emb, eW1, Pbuf, Qbuf);
    }

    w2t_kernel<<<(MD*KPAD + 255)/256, 256, 0, stream>>>(eW2, W2T);

    edge_mfma<<<NROWS*16/16, 256, 0, stream>>>(pairs, counter, Pbuf, Qbuf, coors, feat,
                                               eW1, eb1, W2T, eb2, macc);

    node1_kernel<<<(NROWS*512 + 255)/256, 256, 0, stream>>>(emb, macc, nW1, nb1, hidden);
    node2_kernel<<<(NROWS*DIMC + 255)/256, 256, 0, stream>>>(hidden, nW2, nb2, emb, out_node);
}

// Round 2
// 889.770 us; speedup vs baseline: 3.3806x; 2.4058x over previous
//
#include <hip/hip_runtime.h>
#include <stdint.h>

typedef unsigned short ushort_t;

#define NN    2048
#define DIMC  256
#define H1    1030
#define MD    64
#define NROWS 8192

// edge MFMA tiling
#define KPAD     1088        // 2*544, multiple of 32, >= H1
#define CH       544         // K-chunk held in LDS
#define CH_STEPS 17          // 544/32
#define APAD     552         // LDS row stride (bf16 elems): conflict-free b128

// pq GEMM: N = 2*1030 = 2060, padded to 2112 = 33*64
#define NPQ      2060
#define NPQP     2112
#define KN1      320         // node1 K = 256 + 64
#define KN2      512         // node2 K

typedef __bf16 bf16x8 __attribute__((ext_vector_type(8)));
typedef float  f32x4  __attribute__((ext_vector_type(4)));

__device__ __forceinline__ float bfu2f(ushort_t u){ union{unsigned u; float f;} v; v.u = ((unsigned)u)<<16; return v.f; }
__device__ __forceinline__ ushort_t f2bfu(float f){ union{float f; unsigned u;} v; v.f=f; unsigned r = (v.u + 0x7FFFu + ((v.u>>16)&1u))>>16; return (ushort_t)r; }
__device__ __forceinline__ float siluf(float x){ return x / (1.0f + __expf(-x)); }
__device__ __forceinline__ void split_hilo(float v, ushort_t& hi, ushort_t& lo){
    hi = f2bfu(v);
    lo = f2bfu(v - bfu2f(hi));
}

__global__ void mask_kernel(const int* __restrict__ mask, float* __restrict__ out_mask){
    int t = blockIdx.x*256 + threadIdx.x;
    if (t < NROWS) out_mask[t] = mask[t] ? 1.0f : 0.0f;
}

// ---------------- adj scan: bool->f32 passthrough + neighbor extraction + pair emission ----------------
__global__ void adj_kernel(const int* __restrict__ adj, const int* __restrict__ mask,
                           float* __restrict__ out_adj, int* __restrict__ pairs,
                           int* __restrict__ counter)
{
    const int w = threadIdx.x >> 6, lane = threadIdx.x & 63;
    const int row = blockIdx.x*4 + w;
    const int b = row >> 11, i = row & (NN-1);
    __shared__ int nbrs[4][15];
    int total = 0;
    const size_t rbase = (size_t)row * NN;
    for (int c = 0; c < NN/64; c++) {
        int j = c*64 + lane;
        int v = adj[rbase + j];
        out_adj[rbase + j] = v ? 1.0f : 0.0f;
        bool pred = (v != 0) && (j != i);
        unsigned long long bm = __ballot(pred);
        if (pred) {
            int slot = total + __popcll(bm & ((1ull<<lane)-1ull));
            if (slot < 15) nbrs[w][slot] = j;
        }
        total += __popcll(bm);
    }
    int cnt = total < 15 ? total : 15;
    if (mask[row] != 0) {
        int jl = (lane < cnt) ? nbrs[w][lane] : 0;
        bool ok = (lane < cnt) && (mask[b*NN + jl] != 0);
        unsigned long long bm = __ballot(ok);
        int npair = 1 + __popcll(bm);
        int basep = 0;
        if (lane == 0) basep = atomicAdd(counter, npair);
        basep = __shfl(basep, 0);
        if (lane == 0) pairs[basep] = (row << 16) | i;      // self pair
        if (ok) {
            int pos = basep + 1 + __popcll(bm & ((1ull<<lane)-1ull));
            pairs[pos] = (row << 16) | jl;
        }
    }
}

// ================= shared MFMA 16x64 tile: C[16][64] += A[16][K] * B[64][K]^T ===========
// A,B bf16 split hi/lo; 3 passes (hi*hi, hi*lo, lo*hi); lo*lo negligible (~2^-18 rel).
// Fragment map (verified in edge_mfma): lane l: A-row = l&15, k = (l>>4)*8..+8;
// D: col = l&15, row = (l>>4)*4 + reg.
template<int K>
__device__ __forceinline__ void mfma_tile(const ushort_t* __restrict__ Ah, const ushort_t* __restrict__ Al, int sA,
                                          const ushort_t* __restrict__ Bh, const ushort_t* __restrict__ Bl, int sB,
                                          int lane, f32x4 acc[4])
{
    const int m16 = lane & 15, kg = lane >> 4;
    const ushort_t* arh = Ah + (size_t)m16*sA + kg*8;
    const ushort_t* arl = Al + (size_t)m16*sA + kg*8;
    const ushort_t* brh = Bh + (size_t)m16*sB + kg*8;
    const ushort_t* brl = Bl + (size_t)m16*sB + kg*8;
#pragma unroll 4
    for (int ks = 0; ks < K/32; ks++) {
        bf16x8 ah = *reinterpret_cast<const bf16x8*>(arh + ks*32);
        bf16x8 al = *reinterpret_cast<const bf16x8*>(arl + ks*32);
#pragma unroll
        for (int nf = 0; nf < 4; nf++) {
            bf16x8 bh = *reinterpret_cast<const bf16x8*>(brh + (size_t)(nf*16)*sB + ks*32);
            bf16x8 bl = *reinterpret_cast<const bf16x8*>(brl + (size_t)(nf*16)*sB + ks*32);
            acc[nf] = __builtin_amdgcn_mfma_f32_16x16x32_bf16(ah, bh, acc[nf], 0, 0, 0);
            acc[nf] = __builtin_amdgcn_mfma_f32_16x16x32_bf16(ah, bl, acc[nf], 0, 0, 0);
            acc[nf] = __builtin_amdgcn_mfma_f32_16x16x32_bf16(al, bh, acc[nf], 0, 0, 0);
        }
    }
}

// ---------------- prep kernels: pack operands as bf16 hi/lo ----------------
__global__ void prep_emb(const float* __restrict__ emb, ushort_t* __restrict__ Ah, ushort_t* __restrict__ Al){
    int t = blockIdx.x*256 + threadIdx.x;
    if (t >= NROWS*DIMC) return;
    int r = t >> 8, k = t & 255;
    ushort_t hi, lo; split_hilo(emb[t], hi, lo);
    Ah[(size_t)r*KN1 + k] = hi; Al[(size_t)r*KN1 + k] = lo;
}

__global__ void prep_macc(const float* __restrict__ macc, ushort_t* __restrict__ Ah, ushort_t* __restrict__ Al){
    int t = blockIdx.x*256 + threadIdx.x;
    if (t >= NROWS*MD) return;
    int r = t >> 6, k = t & 63;
    ushort_t hi, lo; split_hilo(macc[t], hi, lo);
    Ah[(size_t)r*KN1 + DIMC + k] = hi; Al[(size_t)r*KN1 + DIMC + k] = lo;
}

// Wpq[n][k], n in [0,2112): n<1030 -> eW1[k][n] (P), n in [1030,2060) -> eW1[256+k][n-1030] (Q), else 0
__global__ void prep_wpq(const float* __restrict__ eW1, ushort_t* __restrict__ Wh, ushort_t* __restrict__ Wl){
    int t = blockIdx.x*256 + threadIdx.x;
    if (t >= NPQP*DIMC) return;
    int n = t >> 8, k = t & 255;
    float v = 0.f;
    if (n < H1) v = eW1[(size_t)k*H1 + n];
    else if (n < NPQ) v = eW1[(size_t)(256+k)*H1 + (n - H1)];
    ushort_t hi, lo; split_hilo(v, hi, lo);
    Wh[t] = hi; Wl[t] = lo;
}

// nW1 [320][512] -> W1T[n][k], n<512, k<320
__global__ void prep_nw1(const float* __restrict__ nW1, ushort_t* __restrict__ Wh, ushort_t* __restrict__ Wl){
    int t = blockIdx.x*256 + threadIdx.x;
    if (t >= 512*KN1) return;
    int n = t / KN1, k = t - n*KN1;
    ushort_t hi, lo; split_hilo(nW1[(size_t)k*512 + n], hi, lo);
    Wh[t] = hi; Wl[t] = lo;
}

// nW2 [512][256] -> W2T[n][k], n<256, k<512
__global__ void prep_nw2(const float* __restrict__ nW2, ushort_t* __restrict__ Wh, ushort_t* __restrict__ Wl){
    int t = blockIdx.x*256 + threadIdx.x;
    if (t >= 256*KN2) return;
    int n = t >> 9, k = t & 511;
    ushort_t hi, lo; split_hilo(nW2[(size_t)k*256 + n], hi, lo);
    Wh[t] = hi; Wl[t] = lo;
}

// ---------------- P/Q via MFMA: [8192 x 2060] = emb @ [eW1[0:256] | eW1[256:512]] ----------------
__global__ __launch_bounds__(256)
void gemm_pq_mfma(const ushort_t* __restrict__ Aeph, const ushort_t* __restrict__ Aepl,
                  const ushort_t* __restrict__ Wh, const ushort_t* __restrict__ Wl,
                  ushort_t* __restrict__ Pb, ushort_t* __restrict__ Qb)
{
    const int lane = threadIdx.x & 63, w = threadIdx.x >> 6;
    const int rowBase = blockIdx.x*64 + w*16;
    const int colBase = blockIdx.y*64;
    f32x4 acc[4] = {{0,0,0,0},{0,0,0,0},{0,0,0,0},{0,0,0,0}};
    mfma_tile<DIMC>(Aeph + (size_t)rowBase*KN1, Aepl + (size_t)rowBase*KN1, KN1,
                    Wh + (size_t)colBase*DIMC, Wl + (size_t)colBase*DIMC, DIMC, lane, acc);
    const int m16 = lane & 15, kg = lane >> 4;
#pragma unroll
    for (int nf = 0; nf < 4; nf++) {
#pragma unroll
        for (int r = 0; r < 4; r++) {
            int row = rowBase + kg*4 + r;
            int n = colBase + nf*16 + m16;
            ushort_t v = f2bfu(acc[nf][r]);
            if (n < H1)        Pb[(size_t)row*H1 + n] = v;
            else if (n < NPQ)  Qb[(size_t)row*H1 + (n - H1)] = v;
        }
    }
}

// ---------------- node1 via MFMA: hidden = silu([emb||m_i] @ nW1 + nb1), out bf16 hi/lo ----
__global__ __launch_bounds__(256)
void node1_mfma(const ushort_t* __restrict__ Aeph, const ushort_t* __restrict__ Aepl,
                const ushort_t* __restrict__ W1h, const ushort_t* __restrict__ W1l,
                const float* __restrict__ nb1, ushort_t* __restrict__ Hh, ushort_t* __restrict__ Hl)
{
    const int lane = threadIdx.x & 63, w = threadIdx.x >> 6;
    const int rowBase = blockIdx.x*64 + w*16;
    const int colBase = blockIdx.y*64;
    f32x4 acc[4] = {{0,0,0,0},{0,0,0,0},{0,0,0,0},{0,0,0,0}};
    mfma_tile<KN1>(Aeph + (size_t)rowBase*KN1, Aepl + (size_t)rowBase*KN1, KN1,
                   W1h + (size_t)colBase*KN1, W1l + (size_t)colBase*KN1, KN1, lane, acc);
    const int m16 = lane & 15, kg = lane >> 4;
#pragma unroll
    for (int nf = 0; nf < 4; nf++) {
#pragma unroll
        for (int r = 0; r < 4; r++) {
            int row = rowBase + kg*4 + r;
            int col = colBase + nf*16 + m16;
            float s = siluf(acc[nf][r] + nb1[col]);
            ushort_t hi, lo; split_hilo(s, hi, lo);
            Hh[(size_t)row*KN2 + col] = hi;
            Hl[(size_t)row*KN2 + col] = lo;
        }
    }
}

// ---------------- node2 via MFMA: out = hidden @ nW2 + nb2 + emb (f32) ----------------
__global__ __launch_bounds__(256)
void node2_mfma(const ushort_t* __restrict__ Hh, const ushort_t* __restrict__ Hl,
                const ushort_t* __restrict__ W2h, const ushort_t* __restrict__ W2l,
                const float* __restrict__ nb2, const float* __restrict__ emb,
                float* __restrict__ out_node)
{
    const int lane = threadIdx.x & 63, w = threadIdx.x >> 6;
    const int rowBase = blockIdx.x*64 + w*16;
    const int colBase = blockIdx.y*64;
    f32x4 acc[4] = {{0,0,0,0},{0,0,0,0},{0,0,0,0},{0,0,0,0}};
    mfma_tile<KN2>(Hh + (size_t)rowBase*KN2, Hl + (size_t)rowBase*KN2, KN2,
                   W2h + (size_t)colBase*KN2, W2l + (size_t)colBase*KN2, KN2, lane, acc);
    const int m16 = lane & 15, kg = lane >> 4;
#pragma unroll
    for (int nf = 0; nf < 4; nf++) {
#pragma unroll
        for (int r = 0; r < 4; r++) {
            int row = rowBase + kg*4 + r;
            int col = colBase + nf*16 + m16;
            size_t o = (size_t)row*DIMC + col;
            out_node[o] = acc[nf][r] + nb2[col] + emb[o];
        }
    }
}

// ---------------- eW2 transpose to bf16 [MD][KPAD], zero-padded for k >= H1 (edge kernel) ----
__global__ void w2t_kernel(const float* __restrict__ eW2, ushort_t* __restrict__ W2T)
{
    int t = blockIdx.x*256 + threadIdx.x;
    if (t >= MD*KPAD) return;
    int n = t / KPAD, k = t - n*KPAD;
    float v = (k < H1) ? eW2[(size_t)k*MD + n] : 0.0f;
    W2T[t] = f2bfu(v);
}

// ---------------- edge MLP, 16 pairs per block, MFMA for h @ eW2 ----------------
__global__ __launch_bounds__(256)
void edge_mfma(const int* __restrict__ pairs, const int* __restrict__ counter,
               const ushort_t* __restrict__ P, const ushort_t* __restrict__ Q,
               const float* __restrict__ coors, const float* __restrict__ feat,
               const float* __restrict__ eW1, const float* __restrict__ eb1,
               const ushort_t* __restrict__ W2T, const float* __restrict__ eb2,
               float* __restrict__ macc)
{
    const int np = counter[0];
    const int base = blockIdx.x * 16;
    if (base >= np) return;

    __shared__ ushort_t Ahi[16][APAD];
    __shared__ ushort_t Alo[16][APAD];
    __shared__ int   s_row[16];
    __shared__ int   s_jr[16];
    __shared__ int   s_val[16];
    __shared__ float s_d[16], s_f0[16], s_f1[16];

    const int t = threadIdx.x;
    const int lane = t & 63;
    const int w = t >> 6;            // wave id 0..3

    if (t < 16) {
        int ip = base + t;
        int valid = (ip < np) ? 1 : 0;
        int e = valid ? pairs[ip] : 0;
        int row = e >> 16, j = e & 0xFFFF;
        int jr = ((row >> 11) << 11) + j;
        float dx = coors[(size_t)row*3+0] - coors[(size_t)jr*3+0];
        float dy = coors[(size_t)row*3+1] - coors[(size_t)jr*3+1];
        float dz = coors[(size_t)row*3+2] - coors[(size_t)jr*3+2];
        size_t fo = ((size_t)row*NN + j)*2;
        s_row[t] = row; s_jr[t] = jr; s_val[t] = valid;
        s_d[t] = dx*dx + dy*dy + dz*dz;
        s_f0[t] = feat[fo]; s_f1[t] = feat[fo+1];
    }
    __syncthreads();

    int prow[4], pjr[4];
    float pd[4], pf0[4], pf1[4];
#pragma unroll
    for (int p4 = 0; p4 < 4; p4++) {
        int p = w*4 + p4;
        prow[p4] = s_row[p]; pjr[p4] = s_jr[p];
        pd[p4] = s_d[p]; pf0[p4] = s_f0[p]; pf1[p4] = s_f1[p];
    }

    const float* w512 = eW1 + (size_t)512*H1;
    const float* w513 = eW1 + (size_t)513*H1;
    const float* w514 = eW1 + (size_t)514*H1;

    f32x4 acc = {0.f, 0.f, 0.f, 0.f};

    const int m16  = lane & 15;
    const int kg   = lane >> 4;
    const int ncol = w*16 + m16;
    const ushort_t* wrowbase = W2T + (size_t)ncol * KPAD + kg*8;

    for (int chunk = 0; chunk < 2; chunk++) {
        const int c0 = chunk * CH;
        for (int i = 0; i < 9; i++) {
            int c = i*64 + lane;
            if (c < CH) {
                int cc = c0 + c;
                bool inK = cc < H1;
                float a512 = 0.f, a513 = 0.f, a514 = 0.f, ab = 0.f;
                if (inK) { a512 = w512[cc]; a513 = w513[cc]; a514 = w514[cc]; ab = eb1[cc]; }
#pragma unroll
                for (int p4 = 0; p4 < 4; p4++) {
                    float h = 0.f;
                    if (inK) {
                        float pv = bfu2f(P[(size_t)prow[p4]*H1 + cc]);
                        float qv = bfu2f(Q[(size_t)pjr[p4]*H1 + cc]);
                        float x = pv + qv + pd[p4]*a512 + pf0[p4]*a513 + pf1[p4]*a514 + ab;
                        h = siluf(x);
                    }
                    ushort_t hi = f2bfu(h);
                    float hif = bfu2f(hi);
                    ushort_t lo = f2bfu(h - hif);
                    int p = w*4 + p4;
                    Ahi[p][c] = hi;
                    Alo[p][c] = lo;
                }
            }
        }
        __syncthreads();
        const ushort_t* wrow = wrowbase + c0;
#pragma unroll 4
        for (int ks = 0; ks < CH_STEPS; ks++) {
            int k = ks*32 + kg*8;
            bf16x8 ahi = *reinterpret_cast<const bf16x8*>(&Ahi[m16][k]);
            bf16x8 alo = *reinterpret_cast<const bf16x8*>(&Alo[m16][k]);
            bf16x8 bfr = *reinterpret_cast<const bf16x8*>(wrow + ks*32);
            acc = __builtin_amdgcn_mfma_f32_16x16x32_bf16(ahi, bfr, acc, 0, 0, 0);
            acc = __builtin_amdgcn_mfma_f32_16x16x32_bf16(alo, bfr, acc, 0, 0, 0);
        }
        __syncthreads();
    }

    {
        float bias = eb2[ncol];
#pragma unroll
        for (int r = 0; r < 4; r++) {
            int p = kg*4 + r;
            if (s_val[p]) {
                float m = siluf(acc[r] + bias);
                atomicAdd(&macc[(size_t)s_row[p]*MD + ncol], m);
            }
        }
    }
}

extern "C" void kernel_launch(void* const* d_in, const int* in_sizes, int n_in,
                              void* d_out, int out_size, void* d_ws, size_t ws_size,
                              hipStream_t stream)
{
    const float* emb   = (const float*)d_in[0];
    const float* coors = (const float*)d_in[1];
    const int*   adj   = (const int*)d_in[2];
    const float* feat  = (const float*)d_in[3];
    const int*   mask  = (const int*)d_in[4];
    const float* eW1   = (const float*)d_in[5];
    const float* eb1   = (const float*)d_in[6];
    const float* eW2   = (const float*)d_in[7];
    const float* eb2   = (const float*)d_in[8];
    const float* nW1   = (const float*)d_in[9];
    const float* nb1   = (const float*)d_in[10];
    const float* nW2   = (const float*)d_in[11];
    const float* nb2   = (const float*)d_in[12];

    float* out       = (float*)d_out;
    float* out_node  = out;               // [4,2048,256]   2,097,152
    float* out_coors = out + 2097152;     // [4,2048,3]        24,576
    float* out_adj   = out + 2121728;     // [4,2048,2048] 16,777,216
    float* out_feat  = out + 18898944;    // [4,2048,2048,2] 33,554,432
    float* out_mask  = out + 52453376;    // [4,2048]           8,192

    char* ws = (char*)d_ws;
    int*      counter = (int*)(ws + 0);            // 256 B
    float*    macc    = (float*)(ws + 256);        // 8192x64 f32 -> ends 2,097,408
    int*      pairs   = (int*)(ws + 2097408);      // 131072 ints -> ends 2,621,696
    ushort_t* Pbuf    = (ushort_t*)(ws + 2621696); // 8192x1030 bf16 -> ends 19,497,216
    ushort_t* Qbuf    = (ushort_t*)(ws + 19497216);// 8192x1030 bf16 -> ends 36,372,736

    // Scratch parked in the out_feat region (134 MB). It is consumed by the GEMM chain and
    // fully overwritten by the final feat D2D memcpy (moved to AFTER node2).
    char* scr = (char*)out_feat;
    ushort_t* Aep_h = (ushort_t*)(scr + 0);         // [8192][320] bf16 hi (emb cols 0..256, macc 256..320)
    ushort_t* Aep_l = (ushort_t*)(scr + 5242880);   // [8192][320] bf16 lo
    ushort_t* Wpq_h = (ushort_t*)(scr + 10485760);  // [2112][256]
    ushort_t* Wpq_l = (ushort_t*)(scr + 11567104);
    ushort_t* W1T_h = (ushort_t*)(scr + 12648448);  // [512][320]
    ushort_t* W1T_l = (ushort_t*)(scr + 12976128);
    ushort_t* NW2T_h= (ushort_t*)(scr + 13303808);  // [256][512]
    ushort_t* NW2T_l= (ushort_t*)(scr + 13565952);
    ushort_t* Hid_h = (ushort_t*)(scr + 13828096);  // [8192][512]
    ushort_t* Hid_l = (ushort_t*)(scr + 22216704);  // ends 30,605,312 < 134,217,728

    // W2T (edge eW2^T bf16 [64][1088]) parked in out_node region; consumed by edge_mfma,
    // fully overwritten afterwards by node2_mfma.
    ushort_t* W2T = (ushort_t*)out_node;

    hipMemsetAsync(counter, 0, 256, stream);
    hipMemsetAsync(macc, 0, (size_t)NROWS*MD*sizeof(float), stream);

    hipMemcpyAsync(out_coors, coors, (size_t)24576*sizeof(float), hipMemcpyDeviceToDevice, stream);

    mask_kernel<<<(NROWS + 255)/256, 256, 0, stream>>>(mask, out_mask);
    adj_kernel<<<NROWS/4, 256, 0, stream>>>(adj, mask, out_adj, pairs, counter);

    // pack operands
    prep_emb<<<(NROWS*DIMC + 255)/256, 256, 0, stream>>>(emb, Aep_h, Aep_l);
    prep_wpq<<<(NPQP*DIMC + 255)/256, 256, 0, stream>>>(eW1, Wpq_h, Wpq_l);
    prep_nw1<<<(512*KN1 + 255)/256, 256, 0, stream>>>(nW1, W1T_h, W1T_l);
    prep_nw2<<<(256*KN2 + 255)/256, 256, 0, stream>>>(nW2, NW2T_h, NW2T_l);
    w2t_kernel<<<(MD*KPAD + 255)/256, 256, 0, stream>>>(eW2, W2T);

    // P/Q GEMM (MFMA)
    gemm_pq_mfma<<<dim3(NROWS/64, NPQP/64), 256, 0, stream>>>(Aep_h, Aep_l, Wpq_h, Wpq_l, Pbuf, Qbuf);

    // edge phase
    edge_mfma<<<NROWS*16/16, 256, 0, stream>>>(pairs, counter, Pbuf, Qbuf, coors, feat,
                                               eW1, eb1, W2T, eb2, macc);

    // node MLP (MFMA)
    prep_macc<<<(NROWS*MD + 255)/256, 256, 0, stream>>>(macc, Aep_h, Aep_l);
    node1_mfma<<<dim3(NROWS/64, 512/64), 256, 0, stream>>>(Aep_h, Aep_l, W1T_h, W1T_l, nb1, Hid_h, Hid_l);
    node2_mfma<<<dim3(NROWS/64, DIMC/64), 256, 0, stream>>>(Hid_h, Hid_l, NW2T_h, NW2T_l, nb2, emb, out_node);

    // feat passthrough LAST: its region doubled as GEMM scratch above
    hipMemcpyAsync(out_feat, feat, (size_t)33554432*sizeof(float), hipMemcpyDeviceToDevice, stream);
}

// Round 5
// 770.253 us; speedup vs baseline: 3.9051x; 1.1552x over previous
//
#include <hip/hip_runtime.h>
#include <stdint.h>

typedef unsigned short ushort_t;

#define NN    2048
#define DIMC  256
#define H1    1030
#define MD    64
#define NROWS 8192

// P/Q row stride (bf16 elems), padded so vector loads never cross rows
#define HP       1040

// edge MFMA tiling
#define KPAD     1152        // 4*288, multiple of 32, >= H1
#define CH       288         // K-chunk held in LDS (288/32 = 9 MFMA steps)
#define CH_STEPS 9
#define NCHUNK   4
#define APAD     296         // LDS row stride: 592B = 148 dw, 148%32=20 -> 2-way (free)
#define GPC      36          // col-groups of 8 per chunk (288/8)

// pq GEMM: N = 2*1030 = 2060, padded to 2112 = 33*64
#define NPQ      2060
#define NPQP     2112
#define KN1      320         // node1 K = 256 + 64
#define KN2      512         // node2 K

typedef __bf16 bf16x8 __attribute__((ext_vector_type(8)));
typedef float  f32x4  __attribute__((ext_vector_type(4)));
typedef float  f32x2  __attribute__((ext_vector_type(2)));
typedef ushort_t u16x8 __attribute__((ext_vector_type(8)));

__device__ __forceinline__ float bfu2f(ushort_t u){ union{unsigned u; float f;} v; v.u = ((unsigned)u)<<16; return v.f; }
__device__ __forceinline__ ushort_t f2bfu(float f){ union{float f; unsigned u;} v; v.f=f; unsigned r = (v.u + 0x7FFFu + ((v.u>>16)&1u))>>16; return (ushort_t)r; }
__device__ __forceinline__ float siluf(float x){ return x / (1.0f + __expf(-x)); }
__device__ __forceinline__ void split_hilo(float v, ushort_t& hi, ushort_t& lo){
    hi = f2bfu(v);
    lo = f2bfu(v - bfu2f(hi));
}

__global__ void mask_kernel(const int* __restrict__ mask, float* __restrict__ out_mask){
    int t = blockIdx.x*256 + threadIdx.x;
    if (t < NROWS) out_mask[t] = mask[t] ? 1.0f : 0.0f;
}

// ---------------- adj scan: bool->f32 passthrough + neighbor extraction + pair emission ----------------
__global__ void adj_kernel(const int* __restrict__ adj, const int* __restrict__ mask,
                           float* __restrict__ out_adj, int* __restrict__ pairs,
                           int* __restrict__ counter)
{
    const int w = threadIdx.x >> 6, lane = threadIdx.x & 63;
    const int row = blockIdx.x*4 + w;
    const int b = row >> 11, i = row & (NN-1);
    __shared__ int nbrs[4][15];
    int total = 0;
    const size_t rbase = (size_t)row * NN;
    for (int c = 0; c < NN/64; c++) {
        int j = c*64 + lane;
        int v = adj[rbase + j];
        out_adj[rbase + j] = v ? 1.0f : 0.0f;
        bool pred = (v != 0) && (j != i);
        unsigned long long bm = __ballot(pred);
        if (pred) {
            int slot = total + __popcll(bm & ((1ull<<lane)-1ull));
            if (slot < 15) nbrs[w][slot] = j;
        }
        total += __popcll(bm);
    }
    int cnt = total < 15 ? total : 15;
    if (mask[row] != 0) {
        int jl = (lane < cnt) ? nbrs[w][lane] : 0;
        bool ok = (lane < cnt) && (mask[b*NN + jl] != 0);
        unsigned long long bm = __ballot(ok);
        int npair = 1 + __popcll(bm);
        int basep = 0;
        if (lane == 0) basep = atomicAdd(counter, npair);
        basep = __shfl(basep, 0);
        if (lane == 0) pairs[basep] = (row << 16) | i;      // self pair
        if (ok) {
            int pos = basep + 1 + __popcll(bm & ((1ull<<lane)-1ull));
            pairs[pos] = (row << 16) | jl;
        }
    }
}

// ================= MFMA 32x64 tile per wave: C[32][64] += A[32][K] * B[64][K]^T ===========
// A,B bf16 split hi/lo; 3 passes (hi*hi, hi*lo, lo*hi); lo*lo negligible.
// Fragment map (harness-verified): lane l: A-row = l&15 (+16 for tile 1), k = (l>>4)*8..+8;
// D: col = l&15, row = (l>>4)*4 + reg.
template<int K>
__device__ __forceinline__ void mfma_tile2(const ushort_t* __restrict__ Ah, const ushort_t* __restrict__ Al, int sA,
                                           const ushort_t* __restrict__ Bh, const ushort_t* __restrict__ Bl, int sB,
                                           int lane, f32x4 (&acc)[2][4])
{
    const int m16 = lane & 15, kg = lane >> 4;
    const ushort_t* a0h = Ah + (size_t)m16*sA + kg*8;
    const ushort_t* a0l = Al + (size_t)m16*sA + kg*8;
    const ushort_t* a1h = a0h + (size_t)16*sA;
    const ushort_t* a1l = a0l + (size_t)16*sA;
    const ushort_t* brh = Bh + (size_t)m16*sB + kg*8;
    const ushort_t* brl = Bl + (size_t)m16*sB + kg*8;
#pragma unroll 4
    for (int ks = 0; ks < K/32; ks++) {
        bf16x8 a0h_ = *reinterpret_cast<const bf16x8*>(a0h + ks*32);
        bf16x8 a0l_ = *reinterpret_cast<const bf16x8*>(a0l + ks*32);
        bf16x8 a1h_ = *reinterpret_cast<const bf16x8*>(a1h + ks*32);
        bf16x8 a1l_ = *reinterpret_cast<const bf16x8*>(a1l + ks*32);
#pragma unroll
        for (int nf = 0; nf < 4; nf++) {
            bf16x8 bh = *reinterpret_cast<const bf16x8*>(brh + (size_t)(nf*16)*sB + ks*32);
            bf16x8 bl = *reinterpret_cast<const bf16x8*>(brl + (size_t)(nf*16)*sB + ks*32);
            acc[0][nf] = __builtin_amdgcn_mfma_f32_16x16x32_bf16(a0h_, bh, acc[0][nf], 0, 0, 0);
            acc[0][nf] = __builtin_amdgcn_mfma_f32_16x16x32_bf16(a0h_, bl, acc[0][nf], 0, 0, 0);
            acc[0][nf] = __builtin_amdgcn_mfma_f32_16x16x32_bf16(a0l_, bh, acc[0][nf], 0, 0, 0);
            acc[1][nf] = __builtin_amdgcn_mfma_f32_16x16x32_bf16(a1h_, bh, acc[1][nf], 0, 0, 0);
            acc[1][nf] = __builtin_amdgcn_mfma_f32_16x16x32_bf16(a1h_, bl, acc[1][nf], 0, 0, 0);
            acc[1][nf] = __builtin_amdgcn_mfma_f32_16x16x32_bf16(a1l_, bh, acc[1][nf], 0, 0, 0);
        }
    }
}

// ---------------- prep kernels ----------------
__global__ void prep_emb(const float* __restrict__ emb, ushort_t* __restrict__ Ah, ushort_t* __restrict__ Al){
    int t = blockIdx.x*256 + threadIdx.x;
    if (t >= NROWS*DIMC) return;
    int r = t >> 8, k = t & 255;
    ushort_t hi, lo; split_hilo(emb[t], hi, lo);
    Ah[(size_t)r*KN1 + k] = hi; Al[(size_t)r*KN1 + k] = lo;
}

__global__ void prep_macc(const float* __restrict__ macc, ushort_t* __restrict__ Ah, ushort_t* __restrict__ Al){
    int t = blockIdx.x*256 + threadIdx.x;
    if (t >= NROWS*MD) return;
    int r = t >> 6, k = t & 63;
    ushort_t hi, lo; split_hilo(macc[t], hi, lo);
    Ah[(size_t)r*KN1 + DIMC + k] = hi; Al[(size_t)r*KN1 + DIMC + k] = lo;
}

// all weight packs fused into one launch (+ padded edge tail rows wt4[4][1040] f32)
__global__ void prep_weights(const float* __restrict__ eW1, const float* __restrict__ nW1,
                             const float* __restrict__ nW2, const float* __restrict__ eW2,
                             const float* __restrict__ eb1,
                             ushort_t* __restrict__ Wpq_h, ushort_t* __restrict__ Wpq_l,
                             ushort_t* __restrict__ W1T_h, ushort_t* __restrict__ W1T_l,
                             ushort_t* __restrict__ NW2T_h, ushort_t* __restrict__ NW2T_l,
                             ushort_t* __restrict__ W2T, float* __restrict__ wt4)
{
    int t = blockIdx.x*256 + threadIdx.x;
    if (t < NPQP*DIMC) {            // Wpq[n][k]: n<1030 -> eW1[k][n] (P), 1030..2059 -> eW1[256+k][n-1030] (Q)
        int n = t >> 8, k = t & 255;
        float v = 0.f;
        if (n < H1) v = eW1[(size_t)k*H1 + n];
        else if (n < NPQ) v = eW1[(size_t)(256+k)*H1 + (n - H1)];
        ushort_t hi, lo; split_hilo(v, hi, lo);
        Wpq_h[t] = hi; Wpq_l[t] = lo;
        return;
    }
    t -= NPQP*DIMC;
    if (t < 512*KN1) {              // W1T[n][k] from nW1[k][n]
        int n = t / KN1, k = t - n*KN1;
        ushort_t hi, lo; split_hilo(nW1[(size_t)k*512 + n], hi, lo);
        W1T_h[t] = hi; W1T_l[t] = lo;
        return;
    }
    t -= 512*KN1;
    if (t < 256*KN2) {              // NW2T[n][k] from nW2[k][n]
        int n = t >> 9, k = t & 511;
        ushort_t hi, lo; split_hilo(nW2[(size_t)k*256 + n], hi, lo);
        NW2T_h[t] = hi; NW2T_l[t] = lo;
        return;
    }
    t -= 256*KN2;
    if (t < MD*KPAD) {              // edge W2T[n][k] bf16, zero pad k>=H1
        int n = t / KPAD, k = t - n*KPAD;
        W2T[t] = f2bfu((k < H1) ? eW2[(size_t)k*MD + n] : 0.0f);
        return;
    }
    t -= MD*KPAD;
    if (t < 4*HP) {                 // wt4[c][k]: c=0..2 -> eW1 rows 512..514, c=3 -> eb1; zero pad k>=H1
        int c = t / HP, k = t - c*HP;
        float v = 0.f;
        if (k < H1) v = (c < 3) ? eW1[(size_t)(512+c)*H1 + k] : eb1[k];
        wt4[t] = v;
    }
}

// ---------------- P/Q via MFMA ----------------
__global__ __launch_bounds__(256)
void gemm_pq_mfma(const ushort_t* __restrict__ Aeph, const ushort_t* __restrict__ Aepl,
                  const ushort_t* __restrict__ Wh, const ushort_t* __restrict__ Wl,
                  ushort_t* __restrict__ Pb, ushort_t* __restrict__ Qb)
{
    const int lane = threadIdx.x & 63, w = threadIdx.x >> 6;
    const int rowBase = blockIdx.x*128 + w*32;
    const int colBase = blockIdx.y*64;
    f32x4 acc[2][4] = {{{0,0,0,0},{0,0,0,0},{0,0,0,0},{0,0,0,0}},
                       {{0,0,0,0},{0,0,0,0},{0,0,0,0},{0,0,0,0}}};
    mfma_tile2<DIMC>(Aeph + (size_t)rowBase*KN1, Aepl + (size_t)rowBase*KN1, KN1,
                     Wh + (size_t)colBase*DIMC, Wl + (size_t)colBase*DIMC, DIMC, lane, acc);
    const int m16 = lane & 15, kg = lane >> 4;
#pragma unroll
    for (int tt = 0; tt < 2; tt++) {
#pragma unroll
        for (int nf = 0; nf < 4; nf++) {
#pragma unroll
            for (int r = 0; r < 4; r++) {
                int row = rowBase + tt*16 + kg*4 + r;
                int n = colBase + nf*16 + m16;
                ushort_t v = f2bfu(acc[tt][nf][r]);
                if (n < H1)        Pb[(size_t)row*HP + n] = v;
                else if (n < NPQ)  Qb[(size_t)row*HP + (n - H1)] = v;
            }
        }
    }
}

// ---------------- node1 via MFMA: hidden = silu([emb||m_i] @ nW1 + nb1), out bf16 hi/lo ----
__global__ __launch_bounds__(256)
void node1_mfma(const ushort_t* __restrict__ Aeph, const ushort_t* __restrict__ Aepl,
                const ushort_t* __restrict__ W1h, const ushort_t* __restrict__ W1l,
                const float* __restrict__ nb1, ushort_t* __restrict__ Hh, ushort_t* __restrict__ Hl)
{
    const int lane = threadIdx.x & 63, w = threadIdx.x >> 6;
    const int rowBase = blockIdx.x*128 + w*32;
    const int colBase = blockIdx.y*64;
    f32x4 acc[2][4] = {{{0,0,0,0},{0,0,0,0},{0,0,0,0},{0,0,0,0}},
                       {{0,0,0,0},{0,0,0,0},{0,0,0,0},{0,0,0,0}}};
    mfma_tile2<KN1>(Aeph + (size_t)rowBase*KN1, Aepl + (size_t)rowBase*KN1, KN1,
                    W1h + (size_t)colBase*KN1, W1l + (size_t)colBase*KN1, KN1, lane, acc);
    const int m16 = lane & 15, kg = lane >> 4;
#pragma unroll
    for (int tt = 0; tt < 2; tt++) {
#pragma unroll
        for (int nf = 0; nf < 4; nf++) {
#pragma unroll
            for (int r = 0; r < 4; r++) {
                int row = rowBase + tt*16 + kg*4 + r;
                int col = colBase + nf*16 + m16;
                float s = siluf(acc[tt][nf][r] + nb1[col]);
                ushort_t hi, lo; split_hilo(s, hi, lo);
                Hh[(size_t)row*KN2 + col] = hi;
                Hl[(size_t)row*KN2 + col] = lo;
            }
        }
    }
}

// ---------------- node2 via MFMA: out = hidden @ nW2 + nb2 + emb (f32) ----------------
__global__ __launch_bounds__(256)
void node2_mfma(const ushort_t* __restrict__ Hh, const ushort_t* __restrict__ Hl,
                const ushort_t* __restrict__ W2h, const ushort_t* __restrict__ W2l,
                const float* __restrict__ nb2, const float* __restrict__ emb,
                float* __restrict__ out_node)
{
    const int lane = threadIdx.x & 63, w = threadIdx.x >> 6;
    const int rowBase = blockIdx.x*128 + w*32;
    const int colBase = blockIdx.y*64;
    f32x4 acc[2][4] = {{{0,0,0,0},{0,0,0,0},{0,0,0,0},{0,0,0,0}},
                       {{0,0,0,0},{0,0,0,0},{0,0,0,0},{0,0,0,0}}};
    mfma_tile2<KN2>(Hh + (size_t)rowBase*KN2, Hl + (size_t)rowBase*KN2, KN2,
                    W2h + (size_t)colBase*KN2, W2l + (size_t)colBase*KN2, KN2, lane, acc);
    const int m16 = lane & 15, kg = lane >> 4;
#pragma unroll
    for (int tt = 0; tt < 2; tt++) {
#pragma unroll
        for (int nf = 0; nf < 4; nf++) {
#pragma unroll
            for (int r = 0; r < 4; r++) {
                int row = rowBase + tt*16 + kg*4 + r;
                int col = colBase + nf*16 + m16;
                size_t o = (size_t)row*DIMC + col;
                out_node[o] = acc[tt][nf][r] + nb2[col] + emb[o];
            }
        }
    }
}

// ---------------- edge MLP, 16 pairs per block, MFMA for h @ eW2 ----------------
// Phase A (vectorized): each lane owns ONE pair (pp=lane>>4) and 8-col groups (sub=lane&15).
// Weight tails come from the zero-padded wt4[4][HP] buffer -> all vector loads in-bounds.
// h stored as bf16 hi + lo via TRUNCATION split (hi+lo ~= f32 exactly; cheap).
__global__ __launch_bounds__(256)
void edge_mfma(const int* __restrict__ pairs, const int* __restrict__ counter,
               const ushort_t* __restrict__ P, const ushort_t* __restrict__ Q,
               const float* __restrict__ coors, const float* __restrict__ feat,
               const float* __restrict__ wt4,
               const ushort_t* __restrict__ W2T, const float* __restrict__ eb2,
               float* __restrict__ macc)
{
    const int np = counter[0];
    const int base = blockIdx.x * 16;
    if (base >= np) return;

    __shared__ __align__(16) ushort_t Ahi[16][APAD];
    __shared__ __align__(16) ushort_t Alo[16][APAD];
    __shared__ int   s_row[16];
    __shared__ int   s_jr[16];
    __shared__ int   s_val[16];
    __shared__ float s_d[16], s_f0[16], s_f1[16];

    const int t = threadIdx.x;
    const int lane = t & 63;
    const int w = t >> 6;            // wave id 0..3

    if (t < 16) {
        int ip = base + t;
        int valid = (ip < np) ? 1 : 0;
        int e = valid ? pairs[ip] : 0;
        int row = e >> 16, j = e & 0xFFFF;
        int jr = ((row >> 11) << 11) + j;
        float dx = coors[(size_t)row*3+0] - coors[(size_t)jr*3+0];
        float dy = coors[(size_t)row*3+1] - coors[(size_t)jr*3+1];
        float dz = coors[(size_t)row*3+2] - coors[(size_t)jr*3+2];
        size_t fo = ((size_t)row*NN + j)*2;
        s_row[t] = row; s_jr[t] = jr; s_val[t] = valid;
        s_d[t] = dx*dx + dy*dy + dz*dz;
        s_f0[t] = feat[fo]; s_f1[t] = feat[fo+1];
    }
    __syncthreads();

    const int pp  = lane >> 4;       // which of this wave's 4 pairs this lane serves (phase A)
    const int sub = lane & 15;       // col-group lane within pair
    const int p   = w*4 + pp;
    const int prow = s_row[p], pjr = s_jr[p];
    const float pd = s_d[p], pf0 = s_f0[p], pf1 = s_f1[p];
    const ushort_t* Prow = P + (size_t)prow*HP;
    const ushort_t* Qrow = Q + (size_t)pjr*HP;

    const float* w512 = wt4 + 0*HP;
    const float* w513 = wt4 + 1*HP;
    const float* w514 = wt4 + 2*HP;
    const float* bia1 = wt4 + 3*HP;

    f32x4 acc = {0.f, 0.f, 0.f, 0.f};

    const int m16  = lane & 15;      // phase B roles
    const int kg   = lane >> 4;
    const int ncol = w*16 + m16;
    const ushort_t* wrowbase = W2T + (size_t)ncol * KPAD + kg*8;

    for (int chunk = 0; chunk < NCHUNK; chunk++) {
        const int c0 = chunk * CH;
        // ---- phase A: 36 col-groups per pair; lane does groups sub, sub+16, sub+32(<36) ----
#pragma unroll
        for (int it = 0; it < 3; it++) {
            int g = sub + it*16;
            if (g < GPC) {
                int cb  = g*8;
                int ccb = c0 + cb;
                u16x8 hv = {0,0,0,0,0,0,0,0};
                u16x8 lv = {0,0,0,0,0,0,0,0};
                if (ccb < H1) {
                    u16x8 pv8 = *reinterpret_cast<const u16x8*>(Prow + ccb);
                    u16x8 qv8 = *reinterpret_cast<const u16x8*>(Qrow + ccb);
                    f32x2 wa[4], wb[4], wc[4], wd[4];
#pragma unroll
                    for (int q = 0; q < 4; q++) {
                        wa[q] = *reinterpret_cast<const f32x2*>(w512 + ccb + q*2);
                        wb[q] = *reinterpret_cast<const f32x2*>(w513 + ccb + q*2);
                        wc[q] = *reinterpret_cast<const f32x2*>(w514 + ccb + q*2);
                        wd[q] = *reinterpret_cast<const f32x2*>(bia1 + ccb + q*2);
                    }
#pragma unroll
                    for (int e = 0; e < 8; e++) {
                        float x = bfu2f(pv8[e]) + bfu2f(qv8[e])
                                + pd*wa[e>>1][e&1] + pf0*wb[e>>1][e&1] + pf1*wc[e>>1][e&1] + wd[e>>1][e&1];
                        float h = (ccb + e < H1) ? siluf(x) : 0.f;
                        union {float f; unsigned u;} cv; cv.f = h;
                        unsigned hib = cv.u & 0xFFFF0000u;
                        hv[e] = (ushort_t)(hib >> 16);
                        union {unsigned u; float f;} hf; hf.u = hib;
                        union {float f; unsigned u;} lw; lw.f = h - hf.f;
                        lv[e] = (ushort_t)(lw.u >> 16);
                    }
                }
                *reinterpret_cast<u16x8*>(&Ahi[p][cb]) = hv;
                *reinterpret_cast<u16x8*>(&Alo[p][cb]) = lv;
            }
        }
        __syncthreads();
        // ---- phase B: acc += A_chunk @ W2T_chunk^T (hi + lo passes) ----
        const ushort_t* wrow = wrowbase + c0;
#pragma unroll
        for (int ks = 0; ks < CH_STEPS; ks++) {
            int k = ks*32 + kg*8;
            bf16x8 ahi = *reinterpret_cast<const bf16x8*>(&Ahi[m16][k]);
            bf16x8 alo = *reinterpret_cast<const bf16x8*>(&Alo[m16][k]);
            bf16x8 bfr = *reinterpret_cast<const bf16x8*>(wrow + ks*32);
            acc = __builtin_amdgcn_mfma_f32_16x16x32_bf16(ahi, bfr, acc, 0, 0, 0);
            acc = __builtin_amdgcn_mfma_f32_16x16x32_bf16(alo, bfr, acc, 0, 0, 0);
        }
        __syncthreads();
    }

    // ---- epilogue: D[m][n], m = kg*4 + r (pair), n = ncol ----
    {
        float bias = eb2[ncol];
#pragma unroll
        for (int r = 0; r < 4; r++) {
            int pe = kg*4 + r;
            if (s_val[pe]) {
                float m = siluf(acc[r] + bias);
                atomicAdd(&macc[(size_t)s_row[pe]*MD + ncol], m);
            }
        }
    }
}

extern "C" void kernel_launch(void* const* d_in, const int* in_sizes, int n_in,
                              void* d_out, int out_size, void* d_ws, size_t ws_size,
                              hipStream_t stream)
{
    const float* emb   = (const float*)d_in[0];
    const float* coors = (const float*)d_in[1];
    const int*   adj   = (const int*)d_in[2];
    const float* feat  = (const float*)d_in[3];
    const int*   mask  = (const int*)d_in[4];
    const float* eW1   = (const float*)d_in[5];
    const float* eb1   = (const float*)d_in[6];
    const float* eW2   = (const float*)d_in[7];
    const float* eb2   = (const float*)d_in[8];
    const float* nW1   = (const float*)d_in[9];
    const float* nb1   = (const float*)d_in[10];
    const float* nW2   = (const float*)d_in[11];
    const float* nb2   = (const float*)d_in[12];

    float* out       = (float*)d_out;
    float* out_node  = out;               // [4,2048,256]   2,097,152
    float* out_coors = out + 2097152;     // [4,2048,3]        24,576
    float* out_adj   = out + 2121728;     // [4,2048,2048] 16,777,216
    float* out_feat  = out + 18898944;    // [4,2048,2048,2] 33,554,432
    float* out_mask  = out + 52453376;    // [4,2048]           8,192

    char* ws = (char*)d_ws;
    int*      counter = (int*)(ws + 0);            // 256 B
    float*    macc    = (float*)(ws + 256);        // 8192x64 f32 -> ends 2,097,408
    int*      pairs   = (int*)(ws + 2097408);      // 131072 ints -> ends 2,621,696
    ushort_t* Pbuf    = (ushort_t*)(ws + 2621696); // 8192x1040 bf16 -> ends 19,661,056
    float*    wt4     = (float*)(ws + 19661056);   // [4][1040] f32 -> ends 19,677,696

    // Scratch parked in the out_feat region (134 MB); consumed by the GEMM chain, then
    // fully overwritten by the final feat D2D memcpy.
    char* scr = (char*)out_feat;
    ushort_t* Aep_h = (ushort_t*)(scr + 0);         // [8192][320] bf16 hi
    ushort_t* Aep_l = (ushort_t*)(scr + 5242880);   // [8192][320] bf16 lo
    ushort_t* Wpq_h = (ushort_t*)(scr + 10485760);  // [2112][256]
    ushort_t* Wpq_l = (ushort_t*)(scr + 11567104);
    ushort_t* W1T_h = (ushort_t*)(scr + 12648448);  // [512][320]
    ushort_t* W1T_l = (ushort_t*)(scr + 12976128);
    ushort_t* NW2T_h= (ushort_t*)(scr + 13303808);  // [256][512]
    ushort_t* NW2T_l= (ushort_t*)(scr + 13565952);
    ushort_t* Hid_h = (ushort_t*)(scr + 13828096);  // [8192][512]
    ushort_t* Hid_l = (ushort_t*)(scr + 22216704);  // ends 30,605,312
    ushort_t* Qbuf  = (ushort_t*)(scr + 30605312);  // [8192][1040] bf16 -> ends 47,644,672

    // W2T (edge eW2^T bf16 [64][1152]) parked in out_node region; consumed by edge_mfma,
    // fully overwritten afterwards by node2_mfma.
    ushort_t* W2T = (ushort_t*)out_node;

    hipMemsetAsync(counter, 0, 256, stream);
    hipMemsetAsync(macc, 0, (size_t)NROWS*MD*sizeof(float), stream);

    hipMemcpyAsync(out_coors, coors, (size_t)24576*sizeof(float), hipMemcpyDeviceToDevice, stream);

    mask_kernel<<<(NROWS + 255)/256, 256, 0, stream>>>(mask, out_mask);
    adj_kernel<<<NROWS/4, 256, 0, stream>>>(adj, mask, out_adj, pairs, counter);

    // pack operands
    prep_emb<<<(NROWS*DIMC + 255)/256, 256, 0, stream>>>(emb, Aep_h, Aep_l);
    {
        int tot = NPQP*DIMC + 512*KN1 + 256*KN2 + MD*KPAD + 4*HP;
        prep_weights<<<(tot + 255)/256, 256, 0, stream>>>(eW1, nW1, nW2, eW2, eb1,
                                                          Wpq_h, Wpq_l, W1T_h, W1T_l,
                                                          NW2T_h, NW2T_l, W2T, wt4);
    }

    // P/Q GEMM (MFMA, 128x64 blocks)
    gemm_pq_mfma<<<dim3(NROWS/128, NPQP/64), 256, 0, stream>>>(Aep_h, Aep_l, Wpq_h, Wpq_l, Pbuf, Qbuf);

    // edge phase
    edge_mfma<<<NROWS*16/16, 256, 0, stream>>>(pairs, counter, Pbuf, Qbuf, coors, feat,
                                               wt4, W2T, eb2, macc);

    // node MLP (MFMA)
    prep_macc<<<(NROWS*MD + 255)/256, 256, 0, stream>>>(macc, Aep_h, Aep_l);
    node1_mfma<<<dim3(NROWS/128, 512/64), 256, 0, stream>>>(Aep_h, Aep_l, W1T_h, W1T_l, nb1, Hid_h, Hid_l);
    node2_mfma<<<dim3(NROWS/128, DIMC/64), 256, 0, stream>>>(Hid_h, Hid_l, NW2T_h, NW2T_l, nb2, emb, out_node);

    // feat passthrough LAST: its region doubled as GEMM scratch above
    hipMemcpyAsync(out_feat, feat, (size_t)33554432*sizeof(float), hipMemcpyDeviceToDevice, stream);
}

// Round 6
// 725.053 us; speedup vs baseline: 4.1485x; 1.0623x over previous
//
#include <hip/hip_runtime.h>
#include <stdint.h>

typedef unsigned short ushort_t;

#define NN    2048
#define DIMC  256
#define H1    1030
#define MD    64
#define NROWS 8192

// P/Q row stride (bf16 elems), padded so vector loads never cross rows
#define HP       1040

// edge MFMA tiling (registers only, no LDS): K padded to 33*32
#define KPAD     1056
#define NKS      33

// pq GEMM: N = 2*1030 = 2060, padded to 2112 = 33*64
#define NPQ      2060
#define NPQP     2112
#define KN1      320         // node1 K = 256 + 64
#define KN2      512         // node2 K

typedef __bf16 bf16x8 __attribute__((ext_vector_type(8)));
typedef float  f32x4  __attribute__((ext_vector_type(4)));
typedef ushort_t u16x8 __attribute__((ext_vector_type(8)));

__device__ __forceinline__ float bfu2f(ushort_t u){ union{unsigned u; float f;} v; v.u = ((unsigned)u)<<16; return v.f; }
__device__ __forceinline__ ushort_t f2bfu(float f){ union{float f; unsigned u;} v; v.f=f; unsigned r = (v.u + 0x7FFFu + ((v.u>>16)&1u))>>16; return (ushort_t)r; }
__device__ __forceinline__ float siluf(float x){ return x / (1.0f + __expf(-x)); }
__device__ __forceinline__ void split_hilo(float v, ushort_t& hi, ushort_t& lo){
    hi = f2bfu(v);
    lo = f2bfu(v - bfu2f(hi));
}

// ---------------- adj scan (int4-vectorized) + mask passthrough + pair emission ----------------
// Selection semantics (VALID_RADIUS=0): self (ranking -1) + adjacency-non-self (ranking 0),
// truncated to the 15 lowest-index adjacency neighbors (top_k K=16, stable ties).
__global__ void adj_kernel(const int* __restrict__ adj, const int* __restrict__ mask,
                           float* __restrict__ out_adj, float* __restrict__ out_mask,
                           int* __restrict__ pairs, int* __restrict__ counter)
{
    const int w = threadIdx.x >> 6, lane = threadIdx.x & 63;
    const int row = blockIdx.x*4 + w;
    const int b = row >> 11, i = row & (NN-1);
    __shared__ int nbrs[4][15];
    int total = 0;
    const size_t rbase = (size_t)row * NN;
    const int4* arow = (const int4*)(adj + rbase);
    float4* orow = (float4*)(out_adj + rbase);
    for (int c = 0; c < NN/256; c++) {          // 8 iters, 4 cols/lane
        int4 v = arow[c*64 + lane];
        int j0 = c*256 + lane*4;
        float4 ov; ov.x = v.x?1.f:0.f; ov.y = v.y?1.f:0.f; ov.z = v.z?1.f:0.f; ov.w = v.w?1.f:0.f;
        orow[c*64 + lane] = ov;
        bool p0 = v.x && (j0   != i);
        bool p1 = v.y && (j0+1 != i);
        bool p2 = v.z && (j0+2 != i);
        bool p3 = v.w && (j0+3 != i);
        unsigned long long b0 = __ballot(p0), b1 = __ballot(p1), b2 = __ballot(p2), b3 = __ballot(p3);
        unsigned long long below = (1ull<<lane)-1ull;
        int slot = total + __popcll(b0&below)+__popcll(b1&below)+__popcll(b2&below)+__popcll(b3&below);
        if (p0 && slot < 15) nbrs[w][slot] = j0;
        slot += p0;
        if (p1 && slot < 15) nbrs[w][slot] = j0+1;
        slot += p1;
        if (p2 && slot < 15) nbrs[w][slot] = j0+2;
        slot += p2;
        if (p3 && slot < 15) nbrs[w][slot] = j0+3;
        total += __popcll(b0)+__popcll(b1)+__popcll(b2)+__popcll(b3);
    }
    int cnt = total < 15 ? total : 15;
    const int mv = mask[row];
    if (lane == 0) out_mask[row] = mv ? 1.0f : 0.0f;
    if (mv != 0) {
        int jl = (lane < cnt) ? nbrs[w][lane] : 0;
        bool ok = (lane < cnt) && (mask[b*NN + jl] != 0);
        unsigned long long bm = __ballot(ok);
        int npair = 1 + __popcll(bm);
        int basep = 0;
        if (lane == 0) basep = atomicAdd(counter, npair);
        basep = __shfl(basep, 0);
        if (lane == 0) pairs[basep] = (row << 16) | i;      // self pair
        if (ok) {
            int pos = basep + 1 + __popcll(bm & ((1ull<<lane)-1ull));
            pairs[pos] = (row << 16) | jl;
        }
    }
}

// ================= MFMA 32x64 tile per wave: C[32][64] += A[32][K] * B[64][K]^T ===========
// A,B bf16 split hi/lo; 3 passes (hi*hi, hi*lo, lo*hi); lo*lo negligible.
template<int K>
__device__ __forceinline__ void mfma_tile2(const ushort_t* __restrict__ Ah, const ushort_t* __restrict__ Al, int sA,
                                           const ushort_t* __restrict__ Bh, const ushort_t* __restrict__ Bl, int sB,
                                           int lane, f32x4 (&acc)[2][4])
{
    const int m16 = lane & 15, kg = lane >> 4;
    const ushort_t* a0h = Ah + (size_t)m16*sA + kg*8;
    const ushort_t* a0l = Al + (size_t)m16*sA + kg*8;
    const ushort_t* a1h = a0h + (size_t)16*sA;
    const ushort_t* a1l = a0l + (size_t)16*sA;
    const ushort_t* brh = Bh + (size_t)m16*sB + kg*8;
    const ushort_t* brl = Bl + (size_t)m16*sB + kg*8;
#pragma unroll 4
    for (int ks = 0; ks < K/32; ks++) {
        bf16x8 a0h_ = *reinterpret_cast<const bf16x8*>(a0h + ks*32);
        bf16x8 a0l_ = *reinterpret_cast<const bf16x8*>(a0l + ks*32);
        bf16x8 a1h_ = *reinterpret_cast<const bf16x8*>(a1h + ks*32);
        bf16x8 a1l_ = *reinterpret_cast<const bf16x8*>(a1l + ks*32);
#pragma unroll
        for (int nf = 0; nf < 4; nf++) {
            bf16x8 bh = *reinterpret_cast<const bf16x8*>(brh + (size_t)(nf*16)*sB + ks*32);
            bf16x8 bl = *reinterpret_cast<const bf16x8*>(brl + (size_t)(nf*16)*sB + ks*32);
            acc[0][nf] = __builtin_amdgcn_mfma_f32_16x16x32_bf16(a0h_, bh, acc[0][nf], 0, 0, 0);
            acc[0][nf] = __builtin_amdgcn_mfma_f32_16x16x32_bf16(a0h_, bl, acc[0][nf], 0, 0, 0);
            acc[0][nf] = __builtin_amdgcn_mfma_f32_16x16x32_bf16(a0l_, bh, acc[0][nf], 0, 0, 0);
            acc[1][nf] = __builtin_amdgcn_mfma_f32_16x16x32_bf16(a1h_, bh, acc[1][nf], 0, 0, 0);
            acc[1][nf] = __builtin_amdgcn_mfma_f32_16x16x32_bf16(a1h_, bl, acc[1][nf], 0, 0, 0);
            acc[1][nf] = __builtin_amdgcn_mfma_f32_16x16x32_bf16(a1l_, bh, acc[1][nf], 0, 0, 0);
        }
    }
}

// ---------------- prep: all weight packs + emb pack fused in one launch ----------------
__global__ void prep_weights(const float* __restrict__ eW1, const float* __restrict__ nW1,
                             const float* __restrict__ nW2, const float* __restrict__ eW2,
                             const float* __restrict__ emb,
                             ushort_t* __restrict__ Wpq_h, ushort_t* __restrict__ Wpq_l,
                             ushort_t* __restrict__ W1T_h, ushort_t* __restrict__ W1T_l,
                             ushort_t* __restrict__ NW2T_h, ushort_t* __restrict__ NW2T_l,
                             ushort_t* __restrict__ W2T, float* __restrict__ wt4,
                             ushort_t* __restrict__ Ah, ushort_t* __restrict__ Al)
{
    int t = blockIdx.x*256 + threadIdx.x;
    if (t < NPQP*DIMC) {            // Wpq[n][k]: n<1030 -> eW1[k][n] (P), 1030..2059 -> eW1[256+k][n-1030] (Q)
        int n = t >> 8, k = t & 255;
        float v = 0.f;
        if (n < H1) v = eW1[(size_t)k*H1 + n];
        else if (n < NPQ) v = eW1[(size_t)(256+k)*H1 + (n - H1)];
        ushort_t hi, lo; split_hilo(v, hi, lo);
        Wpq_h[t] = hi; Wpq_l[t] = lo;
        return;
    }
    t -= NPQP*DIMC;
    if (t < 512*KN1) {              // W1T[n][k] from nW1[k][n]
        int n = t / KN1, k = t - n*KN1;
        ushort_t hi, lo; split_hilo(nW1[(size_t)k*512 + n], hi, lo);
        W1T_h[t] = hi; W1T_l[t] = lo;
        return;
    }
    t -= 512*KN1;
    if (t < 256*KN2) {              // NW2T[n][k] from nW2[k][n]
        int n = t >> 9, k = t & 511;
        ushort_t hi, lo; split_hilo(nW2[(size_t)k*256 + n], hi, lo);
        NW2T_h[t] = hi; NW2T_l[t] = lo;
        return;
    }
    t -= 256*KN2;
    if (t < MD*KPAD) {              // edge W2T[n][k] bf16, zero pad k>=H1
        int n = t / KPAD, k = t - n*KPAD;
        W2T[t] = f2bfu((k < H1) ? eW2[(size_t)k*MD + n] : 0.0f);
        return;
    }
    t -= MD*KPAD;
    if (t < 3*HP) {                 // wt4[c][k]: eW1 rows 512..514, zero pad k>=H1
        int c = t / HP, k = t - c*HP;
        wt4[t] = (k < H1) ? eW1[(size_t)(512+c)*H1 + k] : 0.f;
        return;
    }
    t -= 3*HP;
    if (t < NROWS*DIMC) {           // emb pack -> Aep hi/lo rows [r][0..256)
        int r = t >> 8, k = t & 255;
        ushort_t hi, lo; split_hilo(emb[t], hi, lo);
        Ah[(size_t)r*KN1 + k] = hi; Al[(size_t)r*KN1 + k] = lo;
    }
}

__global__ void prep_macc(const float* __restrict__ macc, ushort_t* __restrict__ Ah, ushort_t* __restrict__ Al){
    int t = blockIdx.x*256 + threadIdx.x;
    if (t >= NROWS*MD) return;
    int r = t >> 6, k = t & 63;
    ushort_t hi, lo; split_hilo(macc[t], hi, lo);
    Ah[(size_t)r*KN1 + DIMC + k] = hi; Al[(size_t)r*KN1 + DIMC + k] = lo;
}

// ---------------- P/Q via MFMA (eb1 folded into P at epilogue) ----------------
__global__ __launch_bounds__(256)
void gemm_pq_mfma(const ushort_t* __restrict__ Aeph, const ushort_t* __restrict__ Aepl,
                  const ushort_t* __restrict__ Wh, const ushort_t* __restrict__ Wl,
                  const float* __restrict__ eb1,
                  ushort_t* __restrict__ Pb, ushort_t* __restrict__ Qb)
{
    const int lane = threadIdx.x & 63, w = threadIdx.x >> 6;
    const int rowBase = blockIdx.x*128 + w*32;
    const int colBase = blockIdx.y*64;
    f32x4 acc[2][4] = {{{0,0,0,0},{0,0,0,0},{0,0,0,0},{0,0,0,0}},
                       {{0,0,0,0},{0,0,0,0},{0,0,0,0},{0,0,0,0}}};
    mfma_tile2<DIMC>(Aeph + (size_t)rowBase*KN1, Aepl + (size_t)rowBase*KN1, KN1,
                     Wh + (size_t)colBase*DIMC, Wl + (size_t)colBase*DIMC, DIMC, lane, acc);
    const int m16 = lane & 15, kg = lane >> 4;
#pragma unroll
    for (int tt = 0; tt < 2; tt++) {
#pragma unroll
        for (int nf = 0; nf < 4; nf++) {
#pragma unroll
            for (int r = 0; r < 4; r++) {
                int row = rowBase + tt*16 + kg*4 + r;
                int n = colBase + nf*16 + m16;
                if (n < H1) {
                    Pb[(size_t)row*HP + n] = f2bfu(acc[tt][nf][r] + eb1[n]);
                } else if (n < NPQ) {
                    Qb[(size_t)row*HP + (n - H1)] = f2bfu(acc[tt][nf][r]);
                }
            }
        }
    }
}

// ---------------- node1 via MFMA: hidden = silu([emb||m_i] @ nW1 + nb1), out bf16 hi/lo ----
__global__ __launch_bounds__(256)
void node1_mfma(const ushort_t* __restrict__ Aeph, const ushort_t* __restrict__ Aepl,
                const ushort_t* __restrict__ W1h, const ushort_t* __restrict__ W1l,
                const float* __restrict__ nb1, ushort_t* __restrict__ Hh, ushort_t* __restrict__ Hl)
{
    const int lane = threadIdx.x & 63, w = threadIdx.x >> 6;
    const int rowBase = blockIdx.x*128 + w*32;
    const int colBase = blockIdx.y*64;
    f32x4 acc[2][4] = {{{0,0,0,0},{0,0,0,0},{0,0,0,0},{0,0,0,0}},
                       {{0,0,0,0},{0,0,0,0},{0,0,0,0},{0,0,0,0}}};
    mfma_tile2<KN1>(Aeph + (size_t)rowBase*KN1, Aepl + (size_t)rowBase*KN1, KN1,
                    W1h + (size_t)colBase*KN1, W1l + (size_t)colBase*KN1, KN1, lane, acc);
    const int m16 = lane & 15, kg = lane >> 4;
#pragma unroll
    for (int tt = 0; tt < 2; tt++) {
#pragma unroll
        for (int nf = 0; nf < 4; nf++) {
#pragma unroll
            for (int r = 0; r < 4; r++) {
                int row = rowBase + tt*16 + kg*4 + r;
                int col = colBase + nf*16 + m16;
                float s = siluf(acc[tt][nf][r] + nb1[col]);
                ushort_t hi, lo; split_hilo(s, hi, lo);
                Hh[(size_t)row*KN2 + col] = hi;
                Hl[(size_t)row*KN2 + col] = lo;
            }
        }
    }
}

// ---------------- node2 via MFMA: out = hidden @ nW2 + nb2 + emb (f32) ----------------
__global__ __launch_bounds__(256)
void node2_mfma(const ushort_t* __restrict__ Hh, const ushort_t* __restrict__ Hl,
                const ushort_t* __restrict__ W2h, const ushort_t* __restrict__ W2l,
                const float* __restrict__ nb2, const float* __restrict__ emb,
                float* __restrict__ out_node)
{
    const int lane = threadIdx.x & 63, w = threadIdx.x >> 6;
    const int rowBase = blockIdx.x*128 + w*32;
    const int colBase = blockIdx.y*64;
    f32x4 acc[2][4] = {{{0,0,0,0},{0,0,0,0},{0,0,0,0},{0,0,0,0}},
                       {{0,0,0,0},{0,0,0,0},{0,0,0,0},{0,0,0,0}}};
    mfma_tile2<KN2>(Hh + (size_t)rowBase*KN2, Hl + (size_t)rowBase*KN2, KN2,
                    W2h + (size_t)colBase*KN2, W2l + (size_t)colBase*KN2, KN2, lane, acc);
    const int m16 = lane & 15, kg = lane >> 4;
#pragma unroll
    for (int tt = 0; tt < 2; tt++) {
#pragma unroll
        for (int nf = 0; nf < 4; nf++) {
#pragma unroll
            for (int r = 0; r < 4; r++) {
                int row = rowBase + tt*16 + kg*4 + r;
                int col = colBase + nf*16 + m16;
                size_t o = (size_t)row*DIMC + col;
                out_node[o] = acc[tt][nf][r] + nb2[col] + emb[o];
            }
        }
    }
}

// ---------------- edge MLP: registers only, no LDS, no barriers ----------------
// Each wave owns 16 pairs. Lane l computes h for pair (l&15) at k = ks*32+(l>>4)*8..+8 —
// exactly the 16x16x32 MFMA A-fragment — so h goes straight from VALU to MFMA in VGPRs.
// h split hi/lo (truncation); B = W2T single bf16; acc[4] covers all 64 output cols.
__global__ __launch_bounds__(256)
void edge_mfma(const int* __restrict__ pairs, const int* __restrict__ counter,
               const ushort_t* __restrict__ P, const ushort_t* __restrict__ Q,
               const float* __restrict__ coors, const float* __restrict__ feat,
               const float* __restrict__ wt4,
               const ushort_t* __restrict__ W2T, const float* __restrict__ eb2,
               float* __restrict__ macc)
{
    const int np = counter[0];
    const int lane = threadIdx.x & 63;
    const int w = threadIdx.x >> 6;
    const int wbase = blockIdx.x*64 + w*16;
    if (wbase >= np) return;
    const int m16 = lane & 15, kg = lane >> 4;

    // per-lane pair metadata (pair = wbase + m16)
    const int pidx = wbase + m16;
    const int e = pairs[(pidx < np) ? pidx : wbase];
    const int row = e >> 16, j = e & 0xFFFF;
    const int jr = ((row >> 11) << 11) + j;
    const float dx = coors[row*3+0] - coors[jr*3+0];
    const float dy = coors[row*3+1] - coors[jr*3+1];
    const float dz = coors[row*3+2] - coors[jr*3+2];
    const float d  = dx*dx + dy*dy + dz*dz;
    const size_t fo = ((size_t)row*NN + j)*2;
    const float f0 = feat[fo], f1 = feat[fo+1];
    const ushort_t* Prow = P + (size_t)row*HP;
    const ushort_t* Qrow = Q + (size_t)jr*HP;
    const float* w512 = wt4;
    const float* w513 = wt4 + HP;
    const float* w514 = wt4 + 2*HP;
    const int kb = kg*8;

    f32x4 acc[4] = {{0,0,0,0},{0,0,0,0},{0,0,0,0},{0,0,0,0}};

    for (int ks = 0; ks < NKS; ks++) {
        const int k0 = ks*32 + kb;
        u16x8 hv = {0,0,0,0,0,0,0,0};
        u16x8 lv = {0,0,0,0,0,0,0,0};
        if (k0 < H1) {
            u16x8 pv8 = *reinterpret_cast<const u16x8*>(Prow + k0);
            u16x8 qv8 = *reinterpret_cast<const u16x8*>(Qrow + k0);
            f32x4 wa0 = *reinterpret_cast<const f32x4*>(w512 + k0);
            f32x4 wa1 = *reinterpret_cast<const f32x4*>(w512 + k0 + 4);
            f32x4 wb0 = *reinterpret_cast<const f32x4*>(w513 + k0);
            f32x4 wb1 = *reinterpret_cast<const f32x4*>(w513 + k0 + 4);
            f32x4 wc0 = *reinterpret_cast<const f32x4*>(w514 + k0);
            f32x4 wc1 = *reinterpret_cast<const f32x4*>(w514 + k0 + 4);
#pragma unroll
            for (int ee = 0; ee < 8; ee++) {
                float va = (ee < 4) ? wa0[ee] : wa1[ee-4];
                float vb = (ee < 4) ? wb0[ee] : wb1[ee-4];
                float vc = (ee < 4) ? wc0[ee] : wc1[ee-4];
                float x = bfu2f(pv8[ee]) + bfu2f(qv8[ee]) + d*va + f0*vb + f1*vc;
                float h = (k0 + ee < H1) ? siluf(x) : 0.f;
                union {float f; unsigned u;} cv; cv.f = h;
                unsigned hib = cv.u & 0xFFFF0000u;
                hv[ee] = (ushort_t)(hib >> 16);
                union {unsigned u; float f;} hf; hf.u = hib;
                union {float f; unsigned u;} lw; lw.f = h - hf.f;
                lv[ee] = (ushort_t)(lw.u >> 16);
            }
        }
        bf16x8 ah = *reinterpret_cast<bf16x8*>(&hv);
        bf16x8 al = *reinterpret_cast<bf16x8*>(&lv);
        const ushort_t* Wk = W2T + k0;
#pragma unroll
        for (int nf = 0; nf < 4; nf++) {
            bf16x8 bfr = *reinterpret_cast<const bf16x8*>(Wk + (size_t)(nf*16 + m16)*KPAD);
            acc[nf] = __builtin_amdgcn_mfma_f32_16x16x32_bf16(ah, bfr, acc[nf], 0, 0, 0);
            acc[nf] = __builtin_amdgcn_mfma_f32_16x16x32_bf16(al, bfr, acc[nf], 0, 0, 0);
        }
    }

    // epilogue: D row = kg*4 + r (pair), col = nf*16 + m16
#pragma unroll
    for (int nf = 0; nf < 4; nf++) {
        const int n = nf*16 + m16;
        const float bias = eb2[n];
#pragma unroll
        for (int r = 0; r < 4; r++) {
            int pe = wbase + kg*4 + r;
            if (pe < np) {
                int rr = pairs[pe] >> 16;
                float m = siluf(acc[nf][r] + bias);
                atomicAdd(&macc[(size_t)rr*MD + n], m);
            }
        }
    }
}

extern "C" void kernel_launch(void* const* d_in, const int* in_sizes, int n_in,
                              void* d_out, int out_size, void* d_ws, size_t ws_size,
                              hipStream_t stream)
{
    const float* emb   = (const float*)d_in[0];
    const float* coors = (const float*)d_in[1];
    const int*   adj   = (const int*)d_in[2];
    const float* feat  = (const float*)d_in[3];
    const int*   mask  = (const int*)d_in[4];
    const float* eW1   = (const float*)d_in[5];
    const float* eb1   = (const float*)d_in[6];
    const float* eW2   = (const float*)d_in[7];
    const float* eb2   = (const float*)d_in[8];
    const float* nW1   = (const float*)d_in[9];
    const float* nb1   = (const float*)d_in[10];
    const float* nW2   = (const float*)d_in[11];
    const float* nb2   = (const float*)d_in[12];

    float* out       = (float*)d_out;
    float* out_node  = out;               // [4,2048,256]   2,097,152
    float* out_coors = out + 2097152;     // [4,2048,3]        24,576
    float* out_adj   = out + 2121728;     // [4,2048,2048] 16,777,216
    float* out_feat  = out + 18898944;    // [4,2048,2048,2] 33,554,432
    float* out_mask  = out + 52453376;    // [4,2048]           8,192

    char* ws = (char*)d_ws;
    int*      counter = (int*)(ws + 0);            // 256 B
    float*    macc    = (float*)(ws + 256);        // 8192x64 f32 -> ends 2,097,408
    int*      pairs   = (int*)(ws + 2097408);      // 131072 ints -> ends 2,621,696
    ushort_t* Pbuf    = (ushort_t*)(ws + 2621696); // 8192x1040 bf16 -> ends 19,661,056
    float*    wt4     = (float*)(ws + 19661056);   // [3][1040] f32 -> ends 19,673,536

    // Scratch parked in the out_feat region (134 MB); consumed by the GEMM chain, then
    // fully overwritten by the final feat D2D memcpy.
    char* scr = (char*)out_feat;
    ushort_t* Aep_h = (ushort_t*)(scr + 0);         // [8192][320] bf16 hi
    ushort_t* Aep_l = (ushort_t*)(scr + 5242880);   // [8192][320] bf16 lo
    ushort_t* Wpq_h = (ushort_t*)(scr + 10485760);  // [2112][256]
    ushort_t* Wpq_l = (ushort_t*)(scr + 11567104);
    ushort_t* W1T_h = (ushort_t*)(scr + 12648448);  // [512][320]
    ushort_t* W1T_l = (ushort_t*)(scr + 12976128);
    ushort_t* NW2T_h= (ushort_t*)(scr + 13303808);  // [256][512]
    ushort_t* NW2T_l= (ushort_t*)(scr + 13565952);
    ushort_t* Hid_h = (ushort_t*)(scr + 13828096);  // [8192][512]
    ushort_t* Hid_l = (ushort_t*)(scr + 22216704);  // ends 30,605,312
    ushort_t* Qbuf  = (ushort_t*)(scr + 30605312);  // [8192][1040] bf16 -> ends 47,644,672

    // W2T (edge eW2^T bf16 [64][1056]) parked in out_node region; consumed by edge_mfma,
    // fully overwritten afterwards by node2_mfma.
    ushort_t* W2T = (ushort_t*)out_node;

    hipMemsetAsync(counter, 0, 256, stream);
    hipMemsetAsync(macc, 0, (size_t)NROWS*MD*sizeof(float), stream);

    hipMemcpyAsync(out_coors, coors, (size_t)24576*sizeof(float), hipMemcpyDeviceToDevice, stream);

    adj_kernel<<<NROWS/4, 256, 0, stream>>>(adj, mask, out_adj, out_mask, pairs, counter);

    {
        int tot = NPQP*DIMC + 512*KN1 + 256*KN2 + MD*KPAD + 3*HP + NROWS*DIMC;
        prep_weights<<<(tot + 255)/256, 256, 0, stream>>>(eW1, nW1, nW2, eW2, emb,
                                                          Wpq_h, Wpq_l, W1T_h, W1T_l,
                                                          NW2T_h, NW2T_l, W2T, wt4,
                                                          Aep_h, Aep_l);
    }

    // P/Q GEMM (MFMA, 128x64 blocks), eb1 folded into P
    gemm_pq_mfma<<<dim3(NROWS/128, NPQP/64), 256, 0, stream>>>(Aep_h, Aep_l, Wpq_h, Wpq_l, eb1, Pbuf, Qbuf);

    // edge phase: 64 pairs per block (16 per wave), max np = 131072 -> 2048 blocks
    edge_mfma<<<2048, 256, 0, stream>>>(pairs, counter, Pbuf, Qbuf, coors, feat,
                                        wt4, W2T, eb2, macc);

    // node MLP (MFMA)
    prep_macc<<<(NROWS*MD + 255)/256, 256, 0, stream>>>(macc, Aep_h, Aep_l);
    node1_mfma<<<dim3(NROWS/128, 512/64), 256, 0, stream>>>(Aep_h, Aep_l, W1T_h, W1T_l, nb1, Hid_h, Hid_l);
    node2_mfma<<<dim3(NROWS/128, DIMC/64), 256, 0, stream>>>(Hid_h, Hid_l, NW2T_h, NW2T_l, nb2, emb, out_node);

    // feat passthrough LAST: its region doubled as GEMM scratch above
    hipMemcpyAsync(out_feat, feat, (size_t)33554432*sizeof(float), hipMemcpyDeviceToDevice, stream);
}

// Round 7
// 698.436 us; speedup vs baseline: 4.3066x; 1.0381x over previous
//
#include <hip/hip_runtime.h>
#include <stdint.h>

typedef unsigned short ushort_t;

#define NN    2048
#define DIMC  256
#define H1    1030
#define MD    64
#define NROWS 8192

// P/Q row stride (bf16 elems), padded so vector loads never cross rows
#define HP       1040

// edge MFMA tiling (registers only, no LDS): K padded to 33*32
#define KPAD     1056
#define NKS      33

// pq GEMM: N = 2*1030 = 2060, padded to 2112 = 33*64
#define NPQ      2060
#define NPQP     2112
#define KN1      320         // node1 K = 256 + 64
#define KN2      512         // node2 K

// stage1 role sizes
#define ADJ_BLKS 2048
#define PREP_TOT (NPQP*DIMC + 512*KN1 + 256*KN2 + MD*KPAD + 3*HP + NROWS*DIMC)  // 3,003,440
#define MACCZ    (NROWS*MD/4)     // 131072 float4
#define COORSZ   (24576/4)        // 6144 float4
// stage5 role sizes
#define N2_BLKS  256
#define FCOPY4   (33554432/4)     // 8,388,608 float4 -> 32768 blocks

typedef __bf16 bf16x8 __attribute__((ext_vector_type(8)));
typedef float  f32x4  __attribute__((ext_vector_type(4)));
typedef ushort_t u16x8 __attribute__((ext_vector_type(8)));

__device__ __forceinline__ float bfu2f(ushort_t u){ union{unsigned u; float f;} v; v.u = ((unsigned)u)<<16; return v.f; }
__device__ __forceinline__ ushort_t f2bfu(float f){ union{float f; unsigned u;} v; v.f=f; unsigned r = (v.u + 0x7FFFu + ((v.u>>16)&1u))>>16; return (ushort_t)r; }
__device__ __forceinline__ float siluf(float x){ return x / (1.0f + __expf(-x)); }
__device__ __forceinline__ void split_hilo(float v, ushort_t& hi, ushort_t& lo){
    hi = f2bfu(v);
    lo = f2bfu(v - bfu2f(hi));
}

// ================= stage1: adj scan + all prep packs + macc zero + coors copy ===============
__global__ void stage1(const int* __restrict__ adj, const int* __restrict__ mask,
                       const float* __restrict__ coors,
                       const float* __restrict__ eW1, const float* __restrict__ nW1,
                       const float* __restrict__ nW2, const float* __restrict__ eW2,
                       const float* __restrict__ emb,
                       float* __restrict__ out_adj, float* __restrict__ out_mask,
                       float* __restrict__ out_coors,
                       int* __restrict__ pairs, int* __restrict__ counter,
                       ushort_t* __restrict__ Wpq_h, ushort_t* __restrict__ Wpq_l,
                       ushort_t* __restrict__ W1T_h, ushort_t* __restrict__ W1T_l,
                       ushort_t* __restrict__ NW2T_h, ushort_t* __restrict__ NW2T_l,
                       ushort_t* __restrict__ W2T, float* __restrict__ wt4,
                       ushort_t* __restrict__ Ah, ushort_t* __restrict__ Al,
                       float* __restrict__ macc)
{
    if (blockIdx.x < ADJ_BLKS) {
        // ---- adj role: 4 rows/block, int4-vectorized, pair emission ----
        const int w = threadIdx.x >> 6, lane = threadIdx.x & 63;
        const int row = blockIdx.x*4 + w;
        const int b = row >> 11, i = row & (NN-1);
        __shared__ int nbrs[4][15];
        int total = 0;
        const size_t rbase = (size_t)row * NN;
        const int4* arow = (const int4*)(adj + rbase);
        float4* orow = (float4*)(out_adj + rbase);
        for (int c = 0; c < NN/256; c++) {
            int4 v = arow[c*64 + lane];
            int j0 = c*256 + lane*4;
            float4 ov; ov.x = v.x?1.f:0.f; ov.y = v.y?1.f:0.f; ov.z = v.z?1.f:0.f; ov.w = v.w?1.f:0.f;
            orow[c*64 + lane] = ov;
            bool p0 = v.x && (j0   != i);
            bool p1 = v.y && (j0+1 != i);
            bool p2 = v.z && (j0+2 != i);
            bool p3 = v.w && (j0+3 != i);
            unsigned long long b0 = __ballot(p0), b1 = __ballot(p1), b2 = __ballot(p2), b3 = __ballot(p3);
            unsigned long long below = (1ull<<lane)-1ull;
            int slot = total + __popcll(b0&below)+__popcll(b1&below)+__popcll(b2&below)+__popcll(b3&below);
            if (p0 && slot < 15) nbrs[w][slot] = j0;
            slot += p0;
            if (p1 && slot < 15) nbrs[w][slot] = j0+1;
            slot += p1;
            if (p2 && slot < 15) nbrs[w][slot] = j0+2;
            slot += p2;
            if (p3 && slot < 15) nbrs[w][slot] = j0+3;
            total += __popcll(b0)+__popcll(b1)+__popcll(b2)+__popcll(b3);
        }
        int cnt = total < 15 ? total : 15;
        const int mv = mask[row];
        if (lane == 0) out_mask[row] = mv ? 1.0f : 0.0f;
        if (mv != 0) {
            int jl = (lane < cnt) ? nbrs[w][lane] : 0;
            bool ok = (lane < cnt) && (mask[b*NN + jl] != 0);
            unsigned long long bm = __ballot(ok);
            int npair = 1 + __popcll(bm);
            int basep = 0;
            if (lane == 0) basep = atomicAdd(counter, npair);
            basep = __shfl(basep, 0);
            if (lane == 0) pairs[basep] = (row << 16) | i;      // self pair
            if (ok) {
                int pos = basep + 1 + __popcll(bm & ((1ull<<lane)-1ull));
                pairs[pos] = (row << 16) | jl;
            }
        }
        return;
    }
    // ---- flat roles ----
    int t = (blockIdx.x - ADJ_BLKS)*256 + threadIdx.x;
    if (t < NPQP*DIMC) {            // Wpq[n][k]
        int n = t >> 8, k = t & 255;
        float v = 0.f;
        if (n < H1) v = eW1[(size_t)k*H1 + n];
        else if (n < NPQ) v = eW1[(size_t)(256+k)*H1 + (n - H1)];
        ushort_t hi, lo; split_hilo(v, hi, lo);
        Wpq_h[t] = hi; Wpq_l[t] = lo;
        return;
    }
    t -= NPQP*DIMC;
    if (t < 512*KN1) {              // W1T[n][k] from nW1[k][n]
        int n = t / KN1, k = t - n*KN1;
        ushort_t hi, lo; split_hilo(nW1[(size_t)k*512 + n], hi, lo);
        W1T_h[t] = hi; W1T_l[t] = lo;
        return;
    }
    t -= 512*KN1;
    if (t < 256*KN2) {              // NW2T[n][k] from nW2[k][n]
        int n = t >> 9, k = t & 511;
        ushort_t hi, lo; split_hilo(nW2[(size_t)k*256 + n], hi, lo);
        NW2T_h[t] = hi; NW2T_l[t] = lo;
        return;
    }
    t -= 256*KN2;
    if (t < MD*KPAD) {              // edge W2T[n][k] bf16, zero pad k>=H1
        int n = t / KPAD, k = t - n*KPAD;
        W2T[t] = f2bfu((k < H1) ? eW2[(size_t)k*MD + n] : 0.0f);
        return;
    }
    t -= MD*KPAD;
    if (t < 3*HP) {                 // wt4[c][k]: eW1 rows 512..514, zero pad k>=H1
        int c = t / HP, k = t - c*HP;
        wt4[t] = (k < H1) ? eW1[(size_t)(512+c)*H1 + k] : 0.f;
        return;
    }
    t -= 3*HP;
    if (t < NROWS*DIMC) {           // emb pack -> Aep hi/lo rows [r][0..256)
        int r = t >> 8, k = t & 255;
        ushort_t hi, lo; split_hilo(emb[t], hi, lo);
        Ah[(size_t)r*KN1 + k] = hi; Al[(size_t)r*KN1 + k] = lo;
        return;
    }
    t -= NROWS*DIMC;
    if (t < MACCZ) {                // macc zero (float4)
        float4 z; z.x = z.y = z.z = z.w = 0.f;
        ((float4*)macc)[t] = z;
        return;
    }
    t -= MACCZ;
    if (t < COORSZ) {               // coors passthrough (float4)
        ((float4*)out_coors)[t] = ((const float4*)coors)[t];
    }
}

// ================= MFMA 32x64 tile per wave: C[32][64] += A[32][K] * B[64][K]^T ===========
template<int K>
__device__ __forceinline__ void mfma_tile2(const ushort_t* __restrict__ Ah, const ushort_t* __restrict__ Al, int sA,
                                           const ushort_t* __restrict__ Bh, const ushort_t* __restrict__ Bl, int sB,
                                           int lane, f32x4 (&acc)[2][4])
{
    const int m16 = lane & 15, kg = lane >> 4;
    const ushort_t* a0h = Ah + (size_t)m16*sA + kg*8;
    const ushort_t* a0l = Al + (size_t)m16*sA + kg*8;
    const ushort_t* a1h = a0h + (size_t)16*sA;
    const ushort_t* a1l = a0l + (size_t)16*sA;
    const ushort_t* brh = Bh + (size_t)m16*sB + kg*8;
    const ushort_t* brl = Bl + (size_t)m16*sB + kg*8;
#pragma unroll 4
    for (int ks = 0; ks < K/32; ks++) {
        bf16x8 a0h_ = *reinterpret_cast<const bf16x8*>(a0h + ks*32);
        bf16x8 a0l_ = *reinterpret_cast<const bf16x8*>(a0l + ks*32);
        bf16x8 a1h_ = *reinterpret_cast<const bf16x8*>(a1h + ks*32);
        bf16x8 a1l_ = *reinterpret_cast<const bf16x8*>(a1l + ks*32);
#pragma unroll
        for (int nf = 0; nf < 4; nf++) {
            bf16x8 bh = *reinterpret_cast<const bf16x8*>(brh + (size_t)(nf*16)*sB + ks*32);
            bf16x8 bl = *reinterpret_cast<const bf16x8*>(brl + (size_t)(nf*16)*sB + ks*32);
            acc[0][nf] = __builtin_amdgcn_mfma_f32_16x16x32_bf16(a0h_, bh, acc[0][nf], 0, 0, 0);
            acc[0][nf] = __builtin_amdgcn_mfma_f32_16x16x32_bf16(a0h_, bl, acc[0][nf], 0, 0, 0);
            acc[0][nf] = __builtin_amdgcn_mfma_f32_16x16x32_bf16(a0l_, bh, acc[0][nf], 0, 0, 0);
            acc[1][nf] = __builtin_amdgcn_mfma_f32_16x16x32_bf16(a1h_, bh, acc[1][nf], 0, 0, 0);
            acc[1][nf] = __builtin_amdgcn_mfma_f32_16x16x32_bf16(a1h_, bl, acc[1][nf], 0, 0, 0);
            acc[1][nf] = __builtin_amdgcn_mfma_f32_16x16x32_bf16(a1l_, bh, acc[1][nf], 0, 0, 0);
        }
    }
}

// ---------------- P/Q via MFMA (eb1 folded into P at epilogue) ----------------
__global__ __launch_bounds__(256)
void gemm_pq_mfma(const ushort_t* __restrict__ Aeph, const ushort_t* __restrict__ Aepl,
                  const ushort_t* __restrict__ Wh, const ushort_t* __restrict__ Wl,
                  const float* __restrict__ eb1,
                  ushort_t* __restrict__ Pb, ushort_t* __restrict__ Qb)
{
    const int lane = threadIdx.x & 63, w = threadIdx.x >> 6;
    const int rowBase = blockIdx.x*128 + w*32;
    const int colBase = blockIdx.y*64;
    f32x4 acc[2][4] = {{{0,0,0,0},{0,0,0,0},{0,0,0,0},{0,0,0,0}},
                       {{0,0,0,0},{0,0,0,0},{0,0,0,0},{0,0,0,0}}};
    mfma_tile2<DIMC>(Aeph + (size_t)rowBase*KN1, Aepl + (size_t)rowBase*KN1, KN1,
                     Wh + (size_t)colBase*DIMC, Wl + (size_t)colBase*DIMC, DIMC, lane, acc);
    const int m16 = lane & 15, kg = lane >> 4;
#pragma unroll
    for (int tt = 0; tt < 2; tt++) {
#pragma unroll
        for (int nf = 0; nf < 4; nf++) {
#pragma unroll
            for (int r = 0; r < 4; r++) {
                int row = rowBase + tt*16 + kg*4 + r;
                int n = colBase + nf*16 + m16;
                if (n < H1) {
                    Pb[(size_t)row*HP + n] = f2bfu(acc[tt][nf][r] + eb1[n]);
                } else if (n < NPQ) {
                    Qb[(size_t)row*HP + (n - H1)] = f2bfu(acc[tt][nf][r]);
                }
            }
        }
    }
}

// ---------------- node1 via MFMA: hidden = silu([emb||m_i] @ nW1 + nb1); macc packed inline ----
__global__ __launch_bounds__(256)
void node1_mfma(const ushort_t* __restrict__ Aeph, const ushort_t* __restrict__ Aepl,
                const ushort_t* __restrict__ W1h, const ushort_t* __restrict__ W1l,
                const float* __restrict__ macc,
                const float* __restrict__ nb1, ushort_t* __restrict__ Hh, ushort_t* __restrict__ Hl)
{
    const int lane = threadIdx.x & 63, w = threadIdx.x >> 6;
    const int rowBase = blockIdx.x*128 + w*32;
    const int colBase = blockIdx.y*64;
    f32x4 acc[2][4] = {{{0,0,0,0},{0,0,0,0},{0,0,0,0},{0,0,0,0}},
                       {{0,0,0,0},{0,0,0,0},{0,0,0,0},{0,0,0,0}}};
    mfma_tile2<DIMC>(Aeph + (size_t)rowBase*KN1, Aepl + (size_t)rowBase*KN1, KN1,
                     W1h + (size_t)colBase*KN1, W1l + (size_t)colBase*KN1, KN1, lane, acc);
    const int m16 = lane & 15, kg = lane >> 4;
    // K extension 256..320 from macc f32, fragments built in registers
    {
        const float* mr0 = macc + (size_t)(rowBase + m16)*MD;
        const float* mr1 = macc + (size_t)(rowBase + 16 + m16)*MD;
        const ushort_t* brh_b = W1h + ((size_t)colBase + m16)*KN1 + DIMC + kg*8;
        const ushort_t* brl_b = W1l + ((size_t)colBase + m16)*KN1 + DIMC + kg*8;
#pragma unroll
        for (int ks = 0; ks < 2; ks++) {
            int kk = ks*32 + kg*8;
            f32x4 va = *reinterpret_cast<const f32x4*>(mr0 + kk);
            f32x4 vb = *reinterpret_cast<const f32x4*>(mr0 + kk + 4);
            f32x4 vc = *reinterpret_cast<const f32x4*>(mr1 + kk);
            f32x4 vd = *reinterpret_cast<const f32x4*>(mr1 + kk + 4);
            u16x8 h0, l0, h1, l1;
#pragma unroll
            for (int e = 0; e < 8; e++) {
                ushort_t hi, lo;
                split_hilo((e < 4) ? va[e] : vb[e-4], hi, lo); h0[e] = hi; l0[e] = lo;
                split_hilo((e < 4) ? vc[e] : vd[e-4], hi, lo); h1[e] = hi; l1[e] = lo;
            }
            bf16x8 a0h = *reinterpret_cast<bf16x8*>(&h0);
            bf16x8 a0l = *reinterpret_cast<bf16x8*>(&l0);
            bf16x8 a1h = *reinterpret_cast<bf16x8*>(&h1);
            bf16x8 a1l = *reinterpret_cast<bf16x8*>(&l1);
#pragma unroll
            for (int nf = 0; nf < 4; nf++) {
                bf16x8 bh = *reinterpret_cast<const bf16x8*>(brh_b + (size_t)(nf*16)*KN1 + ks*32);
                bf16x8 bl = *reinterpret_cast<const bf16x8*>(brl_b + (size_t)(nf*16)*KN1 + ks*32);
                acc[0][nf] = __builtin_amdgcn_mfma_f32_16x16x32_bf16(a0h, bh, acc[0][nf], 0, 0, 0);
                acc[0][nf] = __builtin_amdgcn_mfma_f32_16x16x32_bf16(a0h, bl, acc[0][nf], 0, 0, 0);
                acc[0][nf] = __builtin_amdgcn_mfma_f32_16x16x32_bf16(a0l, bh, acc[0][nf], 0, 0, 0);
                acc[1][nf] = __builtin_amdgcn_mfma_f32_16x16x32_bf16(a1h, bh, acc[1][nf], 0, 0, 0);
                acc[1][nf] = __builtin_amdgcn_mfma_f32_16x16x32_bf16(a1h, bl, acc[1][nf], 0, 0, 0);
                acc[1][nf] = __builtin_amdgcn_mfma_f32_16x16x32_bf16(a1l, bh, acc[1][nf], 0, 0, 0);
            }
        }
    }
#pragma unroll
    for (int tt = 0; tt < 2; tt++) {
#pragma unroll
        for (int nf = 0; nf < 4; nf++) {
#pragma unroll
            for (int r = 0; r < 4; r++) {
                int row = rowBase + tt*16 + kg*4 + r;
                int col = colBase + nf*16 + m16;
                float s = siluf(acc[tt][nf][r] + nb1[col]);
                ushort_t hi, lo; split_hilo(s, hi, lo);
                Hh[(size_t)row*KN2 + col] = hi;
                Hl[(size_t)row*KN2 + col] = lo;
            }
        }
    }
}

// ================= stage5: node2 MFMA + feat passthrough copy =================
__global__ __launch_bounds__(256)
void stage5(const ushort_t* __restrict__ Hh, const ushort_t* __restrict__ Hl,
            const ushort_t* __restrict__ W2h, const ushort_t* __restrict__ W2l,
            const float* __restrict__ nb2, const float* __restrict__ emb,
            const float* __restrict__ feat,
            float* __restrict__ out_node, float* __restrict__ out_feat)
{
    if (blockIdx.x >= N2_BLKS) {
        // feat copy role (float4)
        int t = (blockIdx.x - N2_BLKS)*256 + threadIdx.x;
        if (t < FCOPY4) ((float4*)out_feat)[t] = ((const float4*)feat)[t];
        return;
    }
    const int rb = blockIdx.x & 63, cb = blockIdx.x >> 6;
    const int lane = threadIdx.x & 63, w = threadIdx.x >> 6;
    const int rowBase = rb*128 + w*32;
    const int colBase = cb*64;
    f32x4 acc[2][4] = {{{0,0,0,0},{0,0,0,0},{0,0,0,0},{0,0,0,0}},
                       {{0,0,0,0},{0,0,0,0},{0,0,0,0},{0,0,0,0}}};
    mfma_tile2<KN2>(Hh + (size_t)rowBase*KN2, Hl + (size_t)rowBase*KN2, KN2,
                    W2h + (size_t)colBase*KN2, W2l + (size_t)colBase*KN2, KN2, lane, acc);
    const int m16 = lane & 15, kg = lane >> 4;
#pragma unroll
    for (int tt = 0; tt < 2; tt++) {
#pragma unroll
        for (int nf = 0; nf < 4; nf++) {
#pragma unroll
            for (int r = 0; r < 4; r++) {
                int row = rowBase + tt*16 + kg*4 + r;
                int col = colBase + nf*16 + m16;
                size_t o = (size_t)row*DIMC + col;
                out_node[o] = acc[tt][nf][r] + nb2[col] + emb[o];
            }
        }
    }
}

// ---------------- edge MLP: registers only, no LDS, no barriers ----------------
__global__ __launch_bounds__(256)
void edge_mfma(const int* __restrict__ pairs, const int* __restrict__ counter,
               const ushort_t* __restrict__ P, const ushort_t* __restrict__ Q,
               const float* __restrict__ coors, const float* __restrict__ feat,
               const float* __restrict__ wt4,
               const ushort_t* __restrict__ W2T, const float* __restrict__ eb2,
               float* __restrict__ macc)
{
    const int np = counter[0];
    const int lane = threadIdx.x & 63;
    const int w = threadIdx.x >> 6;
    const int wbase = blockIdx.x*64 + w*16;
    if (wbase >= np) return;
    const int m16 = lane & 15, kg = lane >> 4;

    const int pidx = wbase + m16;
    const int e = pairs[(pidx < np) ? pidx : wbase];
    const int row = e >> 16, j = e & 0xFFFF;
    const int jr = ((row >> 11) << 11) + j;
    const float dx = coors[row*3+0] - coors[jr*3+0];
    const float dy = coors[row*3+1] - coors[jr*3+1];
    const float dz = coors[row*3+2] - coors[jr*3+2];
    const float d  = dx*dx + dy*dy + dz*dz;
    const size_t fo = ((size_t)row*NN + j)*2;
    const float f0 = feat[fo], f1 = feat[fo+1];
    const ushort_t* Prow = P + (size_t)row*HP;
    const ushort_t* Qrow = Q + (size_t)jr*HP;
    const float* w512 = wt4;
    const float* w513 = wt4 + HP;
    const float* w514 = wt4 + 2*HP;
    const int kb = kg*8;

    f32x4 acc[4] = {{0,0,0,0},{0,0,0,0},{0,0,0,0},{0,0,0,0}};

    for (int ks = 0; ks < NKS; ks++) {
        const int k0 = ks*32 + kb;
        u16x8 hv = {0,0,0,0,0,0,0,0};
        u16x8 lv = {0,0,0,0,0,0,0,0};
        if (k0 < H1) {
            u16x8 pv8 = *reinterpret_cast<const u16x8*>(Prow + k0);
            u16x8 qv8 = *reinterpret_cast<const u16x8*>(Qrow + k0);
            f32x4 wa0 = *reinterpret_cast<const f32x4*>(w512 + k0);
            f32x4 wa1 = *reinterpret_cast<const f32x4*>(w512 + k0 + 4);
            f32x4 wb0 = *reinterpret_cast<const f32x4*>(w513 + k0);
            f32x4 wb1 = *reinterpret_cast<const f32x4*>(w513 + k0 + 4);
            f32x4 wc0 = *reinterpret_cast<const f32x4*>(w514 + k0);
            f32x4 wc1 = *reinterpret_cast<const f32x4*>(w514 + k0 + 4);
#pragma unroll
            for (int ee = 0; ee < 8; ee++) {
                float va = (ee < 4) ? wa0[ee] : wa1[ee-4];
                float vb = (ee < 4) ? wb0[ee] : wb1[ee-4];
                float vc = (ee < 4) ? wc0[ee] : wc1[ee-4];
                float x = bfu2f(pv8[ee]) + bfu2f(qv8[ee]) + d*va + f0*vb + f1*vc;
                float h = (k0 + ee < H1) ? siluf(x) : 0.f;
                union {float f; unsigned u;} cv; cv.f = h;
                unsigned hib = cv.u & 0xFFFF0000u;
                hv[ee] = (ushort_t)(hib >> 16);
                union {unsigned u; float f;} hf; hf.u = hib;
                union {float f; unsigned u;} lw; lw.f = h - hf.f;
                lv[ee] = (ushort_t)(lw.u >> 16);
            }
        }
        bf16x8 ah = *reinterpret_cast<bf16x8*>(&hv);
        bf16x8 al = *reinterpret_cast<bf16x8*>(&lv);
        const ushort_t* Wk = W2T + k0;
#pragma unroll
        for (int nf = 0; nf < 4; nf++) {
            bf16x8 bfr = *reinterpret_cast<const bf16x8*>(Wk + (size_t)(nf*16 + m16)*KPAD);
            acc[nf] = __builtin_amdgcn_mfma_f32_16x16x32_bf16(ah, bfr, acc[nf], 0, 0, 0);
            acc[nf] = __builtin_amdgcn_mfma_f32_16x16x32_bf16(al, bfr, acc[nf], 0, 0, 0);
        }
    }

#pragma unroll
    for (int nf = 0; nf < 4; nf++) {
        const int n = nf*16 + m16;
        const float bias = eb2[n];
#pragma unroll
        for (int r = 0; r < 4; r++) {
            int pe = wbase + kg*4 + r;
            if (pe < np) {
                int rr = pairs[pe] >> 16;
                float m = siluf(acc[nf][r] + bias);
                atomicAdd(&macc[(size_t)rr*MD + n], m);
            }
        }
    }
}

extern "C" void kernel_launch(void* const* d_in, const int* in_sizes, int n_in,
                              void* d_out, int out_size, void* d_ws, size_t ws_size,
                              hipStream_t stream)
{
    const float* emb   = (const float*)d_in[0];
    const float* coors = (const float*)d_in[1];
    const int*   adj   = (const int*)d_in[2];
    const float* feat  = (const float*)d_in[3];
    const int*   mask  = (const int*)d_in[4];
    const float* eW1   = (const float*)d_in[5];
    const float* eb1   = (const float*)d_in[6];
    const float* eW2   = (const float*)d_in[7];
    const float* eb2   = (const float*)d_in[8];
    const float* nW1   = (const float*)d_in[9];
    const float* nb1   = (const float*)d_in[10];
    const float* nW2   = (const float*)d_in[11];
    const float* nb2   = (const float*)d_in[12];

    float* out       = (float*)d_out;
    float* out_node  = out;               // [4,2048,256]   2,097,152
    float* out_coors = out + 2097152;     // [4,2048,3]        24,576
    float* out_adj   = out + 2121728;     // [4,2048,2048] 16,777,216
    float* out_feat  = out + 18898944;    // [4,2048,2048,2] 33,554,432
    float* out_mask  = out + 52453376;    // [4,2048]           8,192

    char* ws = (char*)d_ws;
    int*      counter = (int*)(ws + 0);            // 256 B
    float*    macc    = (float*)(ws + 256);        // 8192x64 f32 -> ends 2,097,408
    int*      pairs   = (int*)(ws + 2097408);      // 131072 ints -> ends 2,621,696
    ushort_t* Pbuf    = (ushort_t*)(ws + 2621696); // 8192x1040 bf16 -> ends 19,661,056
    float*    wt4     = (float*)(ws + 19661056);   // [3][1040] f32 -> ends 19,673,536
    ushort_t* Hid_h   = (ushort_t*)(ws + 19673536);// [8192][512] -> ends 28,062,144
    ushort_t* Hid_l   = (ushort_t*)(ws + 28062144);// -> ends 36,450,752
    ushort_t* NW2T_h  = (ushort_t*)(ws + 36450752);// [256][512] -> ends 36,712,896
    ushort_t* NW2T_l  = (ushort_t*)(ws + 36712896);// -> ends 36,975,040

    // Scratch parked in out_feat region; consumed before the stage5 feat-copy overwrites it.
    char* scr = (char*)out_feat;
    ushort_t* Aep_h = (ushort_t*)(scr + 0);         // [8192][320] bf16 hi
    ushort_t* Aep_l = (ushort_t*)(scr + 5242880);   // [8192][320] bf16 lo
    ushort_t* Wpq_h = (ushort_t*)(scr + 10485760);  // [2112][256]
    ushort_t* Wpq_l = (ushort_t*)(scr + 11567104);
    ushort_t* W1T_h = (ushort_t*)(scr + 12648448);  // [512][320]
    ushort_t* W1T_l = (ushort_t*)(scr + 12976128);
    ushort_t* Qbuf  = (ushort_t*)(scr + 13303808);  // [8192][1040] -> ends 30,343,168

    // W2T (edge eW2^T bf16 [64][1056]) parked in out_node region; consumed by edge_mfma,
    // fully overwritten afterwards by stage5's node2 role.
    ushort_t* W2T = (ushort_t*)out_node;

    hipMemsetAsync(counter, 0, 256, stream);

    // stage1: adj + all prep + macc-zero + coors copy
    {
        int extra = (PREP_TOT + MACCZ + COORSZ + 255)/256;
        stage1<<<ADJ_BLKS + extra, 256, 0, stream>>>(adj, mask, coors, eW1, nW1, nW2, eW2, emb,
                                                     out_adj, out_mask, out_coors, pairs, counter,
                                                     Wpq_h, Wpq_l, W1T_h, W1T_l, NW2T_h, NW2T_l,
                                                     W2T, wt4, Aep_h, Aep_l, macc);
    }

    // stage2: P/Q GEMM (MFMA), eb1 folded into P
    gemm_pq_mfma<<<dim3(NROWS/128, NPQP/64), 256, 0, stream>>>(Aep_h, Aep_l, Wpq_h, Wpq_l, eb1, Pbuf, Qbuf);

    // stage3: edge phase
    edge_mfma<<<2048, 256, 0, stream>>>(pairs, counter, Pbuf, Qbuf, coors, feat,
                                        wt4, W2T, eb2, macc);

    // stage4: node1 (macc packed inline)
    node1_mfma<<<dim3(NROWS/128, 512/64), 256, 0, stream>>>(Aep_h, Aep_l, W1T_h, W1T_l, macc, nb1, Hid_h, Hid_l);

    // stage5: node2 + feat passthrough copy
    stage5<<<N2_BLKS + FCOPY4/256, 256, 0, stream>>>(Hid_h, Hid_l, NW2T_h, NW2T_l, nb2, emb, feat,
                                                     out_node, out_feat);
}